// Round 2
// baseline (1462.797 us; speedup 1.0000x reference)
//
#include <hip/hip_runtime.h>
#include <hip/hip_bf16.h>

#define Bn 16
#define Tn 4096
#define IN_DIM 64
#define L 256
#define NL 10
#define PADROWS 512
#define TP (Tn + PADROWS)   // 4608
#define COLS 64

typedef __attribute__((ext_vector_type(8))) short short8;
typedef __attribute__((ext_vector_type(4))) float f32x4;
typedef unsigned short ushort_t;
typedef unsigned int uint_t;

__device__ inline ushort_t f2bf(float f) {
    uint_t u = __builtin_bit_cast(uint_t, f);
    u = u + 0x7fffu + ((u >> 16) & 1u);
    return (ushort_t)(u >> 16);
}

__device__ inline float fexp2f(float x) { return __builtin_amdgcn_exp2f(x); }
__device__ inline float frcpf(float x)  { return __builtin_amdgcn_rcpf(x); }
__device__ inline float tanh_fast(float x) {
    float e = fexp2f(x * 2.8853900817779268f);   // e^(2x)
    return 1.f - 2.f * frcpf(e + 1.f);
}
__device__ inline float sigm_fast(float x) {
    return frcpf(1.f + fexp2f(-1.4426950408889634f * x));
}

__device__ inline f32x4 mfma16(short8 a, short8 b, f32x4 c) {
    return __builtin_amdgcn_mfma_f32_16x16x32_bf16(a, b, c, 0, 0, 0);
}

__device__ inline void gld_lds16(const void* src, void* dst) {
    __builtin_amdgcn_global_load_lds(
        (const __attribute__((address_space(1))) void*)src,
        (__attribute__((address_space(3))) void*)dst, 16, 0, 0);
}

// bijective XCD-chunked swizzle for grid=1024 (1024 % 8 == 0, chunk=128)
__device__ inline int xcd_swz(int bid) {
    return (bid & 7) * 128 + (bid >> 3);
}

// ---------------------------------------------------------------------------
// prep: fp32 weights -> bf16 (with filt/gate k=2 tap concat), zero h pads
// ---------------------------------------------------------------------------
__global__ void prep_kernel(
    const float* __restrict__ filt_w, const float* __restrict__ gate_w,
    const float* __restrict__ res_w,  const float* __restrict__ skip_w,
    const float* __restrict__ emb_w,  const float* __restrict__ fin1_w,
    const float* __restrict__ fin2_w, const float* __restrict__ out_w,
    ushort_t* __restrict__ Wf, ushort_t* __restrict__ Wg,
    ushort_t* __restrict__ Wr, ushort_t* __restrict__ Ws,
    ushort_t* __restrict__ We, ushort_t* __restrict__ W1,
    ushort_t* __restrict__ W2, ushort_t* __restrict__ Wo,
    ushort_t* __restrict__ h_a, ushort_t* __restrict__ h_b)
{
    const int stride = gridDim.x * blockDim.x;
    const int tid0 = blockIdx.x * blockDim.x + threadIdx.x;

    // filt/gate: Wcat[i][o][k]: k<256 -> tap1 (unshifted), k>=256 -> tap0 (shifted)
    for (int idx = tid0; idx < NL * L * 2 * L; idx += stride) {
        int k = idx & 511;
        int o = (idx >> 9) & 255;
        int i = idx >> 17;
        int tap = (k < 256) ? 1 : 0;
        int kk = k & 255;
        int src = ((i * 256 + o) * 256 + kk) * 2 + tap;
        Wf[idx] = f2bf(filt_w[src]);
        Wg[idx] = f2bf(gate_w[src]);
    }
    for (int idx = tid0; idx < NL * L * L; idx += stride)        Wr[idx] = f2bf(res_w[idx]);
    for (int idx = tid0; idx < (NL + 1) * L * L; idx += stride)  Ws[idx] = f2bf(skip_w[idx]);
    for (int idx = tid0; idx < L * IN_DIM; idx += stride)        We[idx] = f2bf(emb_w[idx]);
    for (int idx = tid0; idx < L * L; idx += stride) {
        W1[idx] = f2bf(fin1_w[idx]);
        W2[idx] = f2bf(fin2_w[idx]);
    }
    for (int idx = tid0; idx < 64 * L; idx += stride)            Wo[idx] = f2bf(out_w[idx]);
    // zero the 512-row time pads of both h buffers (front of each batch slab)
    for (int idx = tid0; idx < Bn * PADROWS * L; idx += stride) {
        int bb = idx >> 17;            // 512*256 = 1<<17
        int r = idx & 131071;
        size_t off = (size_t)bb * TP * L + r;
        h_a[off] = 0;
        h_b[off] = 0;
    }
}

// ---------------------------------------------------------------------------
// embedding: h0 = relu(We @ x^T + eb); final = Ws0 @ h0 + sb0
// ---------------------------------------------------------------------------
__global__ __launch_bounds__(512, 4) void emb_kernel(
    const float* __restrict__ x,
    const ushort_t* __restrict__ We, const float* __restrict__ eb,
    const ushort_t* __restrict__ Ws0, const float* __restrict__ sb0,
    ushort_t* __restrict__ h_out, float* __restrict__ fin)
{
    __shared__ __align__(16) char gt[32 * 1024];   // [64][256] bf16, chunk-swizzled

    const int tid = threadIdx.x;
    const int w = tid >> 6;
    const int ln = tid & 63;
    const int q = ln >> 4;
    const int n16 = ln & 15;
    const int lid = xcd_swz(blockIdx.x);
    const int b = lid >> 6;
    const int t0 = (lid & 63) * COLS;
    const int row0 = w * 32;

    f32x4 acc[2][4];
    #pragma unroll
    for (int rt = 0; rt < 2; ++rt)
        #pragma unroll
        for (int ct = 0; ct < 4; ++ct) acc[rt][ct] = (f32x4){0.f, 0.f, 0.f, 0.f};

    #pragma unroll
    for (int ks = 0; ks < 2; ++ks) {
        const int k = ks * 32 + q * 8;
        short8 bfr[4];
        #pragma unroll
        for (int ct = 0; ct < 4; ++ct) {
            int c = ct * 16 + n16;
            const float* xp = x + ((size_t)(b * Tn + t0 + c)) * IN_DIM + k;
            f32x4 x0 = *(const f32x4*)xp;
            f32x4 x1 = *(const f32x4*)(xp + 4);
            short8 v;
            v[0] = (short)f2bf(x0[0]); v[1] = (short)f2bf(x0[1]);
            v[2] = (short)f2bf(x0[2]); v[3] = (short)f2bf(x0[3]);
            v[4] = (short)f2bf(x1[0]); v[5] = (short)f2bf(x1[1]);
            v[6] = (short)f2bf(x1[2]); v[7] = (short)f2bf(x1[3]);
            bfr[ct] = v;
        }
        #pragma unroll
        for (int rt = 0; rt < 2; ++rt) {
            int row = row0 + rt * 16 + n16;
            short8 a = *(const short8*)(We + row * IN_DIM + k);
            #pragma unroll
            for (int ct = 0; ct < 4; ++ct)
                acc[rt][ct] = mfma16(a, bfr[ct], acc[rt][ct]);
        }
    }

    // epilogue: h0 = relu(acc + eb) -> global h + LDS gt
    ushort_t* hob = h_out + ((size_t)(b * TP + PADROWS + t0)) * L;
    #pragma unroll
    for (int rt = 0; rt < 2; ++rt) {
        int i0 = row0 + rt * 16 + q * 4;
        f32x4 eb4 = *(const f32x4*)(eb + i0);
        #pragma unroll
        for (int ct = 0; ct < 4; ++ct) {
            int c = ct * 16 + n16;
            f32x4 h0 = acc[rt][ct] + eb4;
            float v0 = fmaxf(h0[0], 0.f), v1 = fmaxf(h0[1], 0.f);
            float v2 = fmaxf(h0[2], 0.f), v3 = fmaxf(h0[3], 0.f);
            uint_t lo = (uint_t)f2bf(v0) | ((uint_t)f2bf(v1) << 16);
            uint_t hi = (uint_t)f2bf(v2) | ((uint_t)f2bf(v3) << 16);
            *(uint2*)(hob + (size_t)c * L + i0) = make_uint2(lo, hi);
            int byt = c * 512 + ((i0 * 2) ^ ((c & 7) << 4));
            *(uint2*)(gt + byt) = make_uint2(lo, hi);
        }
    }
    __syncthreads();

    // skip0 GEMM over gt
    f32x4 accs[2][4];
    #pragma unroll
    for (int rt = 0; rt < 2; ++rt)
        #pragma unroll
        for (int ct = 0; ct < 4; ++ct) accs[rt][ct] = (f32x4){0.f, 0.f, 0.f, 0.f};

    for (int ks = 0; ks < 8; ++ks) {
        const int k = ks * 32 + q * 8;
        short8 bg[4];
        #pragma unroll
        for (int ct = 0; ct < 4; ++ct) {
            int c = ct * 16 + n16;
            bg[ct] = *(const short8*)(gt + c * 512 + ((k * 2) ^ ((c & 7) << 4)));
        }
        #pragma unroll
        for (int rt = 0; rt < 2; ++rt) {
            int row = row0 + rt * 16 + n16;
            short8 a = *(const short8*)(Ws0 + row * L + k);
            #pragma unroll
            for (int ct = 0; ct < 4; ++ct)
                accs[rt][ct] = mfma16(a, bg[ct], accs[rt][ct]);
        }
    }
    float* fob = fin + ((size_t)(b * Tn + t0)) * L;
    #pragma unroll
    for (int rt = 0; rt < 2; ++rt) {
        int i0 = row0 + rt * 16 + q * 4;
        f32x4 sb4 = *(const f32x4*)(sb0 + i0);
        #pragma unroll
        for (int ct = 0; ct < 4; ++ct) {
            int c = ct * 16 + n16;
            *(f32x4*)(fob + (size_t)c * L + i0) = accs[rt][ct] + sb4;  // first write
        }
    }
}

// ---------------------------------------------------------------------------
// one WaveNet layer.  LDS = hh only (64 KB -> 2 blocks/CU).
//   hh row c (1024B, 64 16B-chunks, slot s holds logical chunk s^(c&7)):
//     chunks  0..31 : h[t0+c][ch]           (res + filt/gate tap1)
//     chunks 32..63 : h[t0+c-d][ch]  phase1 (filt/gate tap0)
//                     gated[c][ch]   phase2 (overwritten after barrier)
// ---------------------------------------------------------------------------
__global__ __launch_bounds__(512, 4) void layer_kernel(
    const ushort_t* __restrict__ h_in, ushort_t* __restrict__ h_out,
    float* __restrict__ fin,
    const ushort_t* __restrict__ Wf, const ushort_t* __restrict__ Wg,
    const ushort_t* __restrict__ Wr, const ushort_t* __restrict__ Ws,
    const float* __restrict__ fb_, const float* __restrict__ gb_,
    const float* __restrict__ rb_, const float* __restrict__ sb_,
    int d)
{
    __shared__ __align__(16) char hh[64 * 1024];

    const int tid = threadIdx.x;
    const int w = tid >> 6;
    const int ln = tid & 63;
    const int q = ln >> 4;
    const int n16 = ln & 15;
    const int lid = xcd_swz(blockIdx.x);
    const int b = lid >> 6;
    const int t0 = (lid & 63) * COLS;
    const int row0 = w * 32;

    // ---- stage hh (global_load_lds, linear dest + pre-swizzled source)
    const ushort_t* hbase = h_in + ((size_t)(b * TP + PADROWS + t0)) * L;
    #pragma unroll
    for (int it = 0; it < 8; ++it) {
        int c = it * 8 + w;                 // wave-uniform row
        int chunk = ln ^ (c & 7);           // pre-swizzled logical 16B-chunk
        int sh = (chunk >= 32) ? d : 0;
        const ushort_t* src = hbase + ((long)c - sh) * L + (chunk & 31) * 8;
        gld_lds16(src, hh + c * 1024);
    }
    __syncthreads();

    // ---- phase 1: filt & gate (K=512 concat GEMMs)
    f32x4 accf[2][4], accg[2][4];
    #pragma unroll
    for (int rt = 0; rt < 2; ++rt)
        #pragma unroll
        for (int ct = 0; ct < 4; ++ct) {
            accf[rt][ct] = (f32x4){0.f, 0.f, 0.f, 0.f};
            accg[rt][ct] = (f32x4){0.f, 0.f, 0.f, 0.f};
        }

    __builtin_amdgcn_s_setprio(1);
    for (int ks = 0; ks < 16; ++ks) {
        const int k = ks * 32 + q * 8;
        short8 bfr[4];
        #pragma unroll
        for (int ct = 0; ct < 4; ++ct) {
            int c = ct * 16 + n16;
            bfr[ct] = *(const short8*)(hh + c * 1024 + ((k * 2) ^ ((c & 7) << 4)));
        }
        #pragma unroll
        for (int rt = 0; rt < 2; ++rt) {
            int row = row0 + rt * 16 + n16;
            short8 af = *(const short8*)(Wf + row * 512 + k);
            short8 ag = *(const short8*)(Wg + row * 512 + k);
            #pragma unroll
            for (int ct = 0; ct < 4; ++ct) {
                accf[rt][ct] = mfma16(af, bfr[ct], accf[rt][ct]);
                accg[rt][ct] = mfma16(ag, bfr[ct], accg[rt][ct]);
            }
        }
    }
    __builtin_amdgcn_s_setprio(0);
    __syncthreads();   // all waves done reading shifted half

    // ---- epilogue 1: gated = tanh(f+fb)*sigmoid(g+gb) -> hh chunks 32..63
    #pragma unroll
    for (int rt = 0; rt < 2; ++rt) {
        int i0 = row0 + rt * 16 + q * 4;
        f32x4 fb4 = *(const f32x4*)(fb_ + i0);
        f32x4 gb4 = *(const f32x4*)(gb_ + i0);
        #pragma unroll
        for (int ct = 0; ct < 4; ++ct) {
            int c = ct * 16 + n16;
            uint_t pk[2];
            #pragma unroll
            for (int h2 = 0; h2 < 2; ++h2) {
                float v0 = tanh_fast(accf[rt][ct][h2 * 2] + fb4[h2 * 2]) *
                           sigm_fast(accg[rt][ct][h2 * 2] + gb4[h2 * 2]);
                float v1 = tanh_fast(accf[rt][ct][h2 * 2 + 1] + fb4[h2 * 2 + 1]) *
                           sigm_fast(accg[rt][ct][h2 * 2 + 1] + gb4[h2 * 2 + 1]);
                pk[h2] = (uint_t)f2bf(v0) | ((uint_t)f2bf(v1) << 16);
            }
            int byt = c * 1024 + ((512 + i0 * 2) ^ ((c & 7) << 4));
            *(uint2*)(hh + byt) = make_uint2(pk[0], pk[1]);
        }
    }
    __syncthreads();

    // ---- phase 2: skip (over gated, chunks 32..63) & res (chunks 0..31)
    f32x4 accs[2][4], accr[2][4];
    #pragma unroll
    for (int rt = 0; rt < 2; ++rt)
        #pragma unroll
        for (int ct = 0; ct < 4; ++ct) {
            accs[rt][ct] = (f32x4){0.f, 0.f, 0.f, 0.f};
            accr[rt][ct] = (f32x4){0.f, 0.f, 0.f, 0.f};
        }

    __builtin_amdgcn_s_setprio(1);
    for (int ks = 0; ks < 8; ++ks) {
        const int k = ks * 32 + q * 8;
        short8 bg[4], bh[4];
        #pragma unroll
        for (int ct = 0; ct < 4; ++ct) {
            int c = ct * 16 + n16;
            bg[ct] = *(const short8*)(hh + c * 1024 + ((512 + k * 2) ^ ((c & 7) << 4)));
            bh[ct] = *(const short8*)(hh + c * 1024 + ((k * 2) ^ ((c & 7) << 4)));
        }
        #pragma unroll
        for (int rt = 0; rt < 2; ++rt) {
            int row = row0 + rt * 16 + n16;
            short8 as_ = *(const short8*)(Ws + row * L + k);
            short8 ar_ = *(const short8*)(Wr + row * L + k);
            #pragma unroll
            for (int ct = 0; ct < 4; ++ct) {
                accs[rt][ct] = mfma16(as_, bg[ct], accs[rt][ct]);
                accr[rt][ct] = mfma16(ar_, bh[ct], accr[rt][ct]);
            }
        }
    }
    __builtin_amdgcn_s_setprio(0);

    // ---- epilogue 2: h' = skip+res (bf16), final += skip (fp32 RMW)
    ushort_t* hob = h_out + ((size_t)(b * TP + PADROWS + t0)) * L;
    float* fob = fin + ((size_t)(b * Tn + t0)) * L;
    #pragma unroll
    for (int rt = 0; rt < 2; ++rt) {
        int i0 = row0 + rt * 16 + q * 4;
        f32x4 sb4 = *(const f32x4*)(sb_ + i0);
        f32x4 rb4 = *(const f32x4*)(rb_ + i0);
        #pragma unroll
        for (int ct = 0; ct < 4; ++ct) {
            int c = ct * 16 + n16;
            f32x4 sk = accs[rt][ct] + sb4;
            f32x4 hn = sk + accr[rt][ct] + rb4;
            uint_t lo = (uint_t)f2bf(hn[0]) | ((uint_t)f2bf(hn[1]) << 16);
            uint_t hi = (uint_t)f2bf(hn[2]) | ((uint_t)f2bf(hn[3]) << 16);
            *(uint2*)(hob + (size_t)c * L + i0) = make_uint2(lo, hi);
            f32x4* fp = (f32x4*)(fob + (size_t)c * L + i0);
            *fp = *fp + sk;
        }
    }
}

// ---------------------------------------------------------------------------
// head: relu->fin1->relu->fin2->out_w->tanh
// ---------------------------------------------------------------------------
__global__ __launch_bounds__(512, 4) void final_kernel(
    const float* __restrict__ fin,
    const ushort_t* __restrict__ W1, const float* __restrict__ b1,
    const ushort_t* __restrict__ W2, const float* __restrict__ b2,
    const ushort_t* __restrict__ Wo, const float* __restrict__ ob,
    float* __restrict__ out)
{
    __shared__ __align__(16) char s1[32 * 1024];
    __shared__ __align__(16) char s2[32 * 1024];

    const int tid = threadIdx.x;
    const int w = tid >> 6;
    const int ln = tid & 63;
    const int q = ln >> 4;
    const int n16 = ln & 15;
    const int lid = xcd_swz(blockIdx.x);
    const int b = lid >> 6;
    const int t0 = (lid & 63) * COLS;
    const int row0 = w * 32;

    // stage s1 = bf16(relu(final))
    {
        int c = tid & 63;
        int kg = tid >> 6;
        const float* fp = fin + ((size_t)(b * Tn + t0 + c)) * L + kg * 32;
        #pragma unroll
        for (int j = 0; j < 8; ++j) {
            f32x4 v = *(const f32x4*)(fp + j * 4);
            uint_t lo = (uint_t)f2bf(fmaxf(v[0], 0.f)) | ((uint_t)f2bf(fmaxf(v[1], 0.f)) << 16);
            uint_t hi = (uint_t)f2bf(fmaxf(v[2], 0.f)) | ((uint_t)f2bf(fmaxf(v[3], 0.f)) << 16);
            int kk = kg * 32 + j * 4;
            *(uint2*)(s1 + c * 512 + ((kk * 2) ^ ((c & 7) << 4))) = make_uint2(lo, hi);
        }
    }
    __syncthreads();

    // GEMM1: z1 = W1 @ s1; relu -> s2
    f32x4 acc[2][4];
    #pragma unroll
    for (int rt = 0; rt < 2; ++rt)
        #pragma unroll
        for (int ct = 0; ct < 4; ++ct) acc[rt][ct] = (f32x4){0.f, 0.f, 0.f, 0.f};
    for (int ks = 0; ks < 8; ++ks) {
        const int k = ks * 32 + q * 8;
        short8 bfr[4];
        #pragma unroll
        for (int ct = 0; ct < 4; ++ct) {
            int c = ct * 16 + n16;
            bfr[ct] = *(const short8*)(s1 + c * 512 + ((k * 2) ^ ((c & 7) << 4)));
        }
        #pragma unroll
        for (int rt = 0; rt < 2; ++rt) {
            int row = row0 + rt * 16 + n16;
            short8 a = *(const short8*)(W1 + row * L + k);
            #pragma unroll
            for (int ct = 0; ct < 4; ++ct) acc[rt][ct] = mfma16(a, bfr[ct], acc[rt][ct]);
        }
    }
    #pragma unroll
    for (int rt = 0; rt < 2; ++rt) {
        int i0 = row0 + rt * 16 + q * 4;
        f32x4 bb = *(const f32x4*)(b1 + i0);
        #pragma unroll
        for (int ct = 0; ct < 4; ++ct) {
            int c = ct * 16 + n16;
            f32x4 z = acc[rt][ct] + bb;
            uint_t lo = (uint_t)f2bf(fmaxf(z[0], 0.f)) | ((uint_t)f2bf(fmaxf(z[1], 0.f)) << 16);
            uint_t hi = (uint_t)f2bf(fmaxf(z[2], 0.f)) | ((uint_t)f2bf(fmaxf(z[3], 0.f)) << 16);
            *(uint2*)(s2 + c * 512 + ((i0 * 2) ^ ((c & 7) << 4))) = make_uint2(lo, hi);
        }
    }
    __syncthreads();

    // GEMM2: z2 = W2 @ s2 (no relu) -> s1
    #pragma unroll
    for (int rt = 0; rt < 2; ++rt)
        #pragma unroll
        for (int ct = 0; ct < 4; ++ct) acc[rt][ct] = (f32x4){0.f, 0.f, 0.f, 0.f};
    for (int ks = 0; ks < 8; ++ks) {
        const int k = ks * 32 + q * 8;
        short8 bfr[4];
        #pragma unroll
        for (int ct = 0; ct < 4; ++ct) {
            int c = ct * 16 + n16;
            bfr[ct] = *(const short8*)(s2 + c * 512 + ((k * 2) ^ ((c & 7) << 4)));
        }
        #pragma unroll
        for (int rt = 0; rt < 2; ++rt) {
            int row = row0 + rt * 16 + n16;
            short8 a = *(const short8*)(W2 + row * L + k);
            #pragma unroll
            for (int ct = 0; ct < 4; ++ct) acc[rt][ct] = mfma16(a, bfr[ct], acc[rt][ct]);
        }
    }
    #pragma unroll
    for (int rt = 0; rt < 2; ++rt) {
        int i0 = row0 + rt * 16 + q * 4;
        f32x4 bb = *(const f32x4*)(b2 + i0);
        #pragma unroll
        for (int ct = 0; ct < 4; ++ct) {
            int c = ct * 16 + n16;
            f32x4 z = acc[rt][ct] + bb;
            uint_t lo = (uint_t)f2bf(z[0]) | ((uint_t)f2bf(z[1]) << 16);
            uint_t hi = (uint_t)f2bf(z[2]) | ((uint_t)f2bf(z[3]) << 16);
            *(uint2*)(s1 + c * 512 + ((i0 * 2) ^ ((c & 7) << 4))) = make_uint2(lo, hi);
        }
    }
    __syncthreads();

    // GEMM3: out = tanh(Wo @ z2 + ob)  (M=64, waves 0..3)
    if (w < 4) {
        f32x4 acc3[4];
        #pragma unroll
        for (int ct = 0; ct < 4; ++ct) acc3[ct] = (f32x4){0.f, 0.f, 0.f, 0.f};
        for (int ks = 0; ks < 8; ++ks) {
            const int k = ks * 32 + q * 8;
            short8 bfr[4];
            #pragma unroll
            for (int ct = 0; ct < 4; ++ct) {
                int c = ct * 16 + n16;
                bfr[ct] = *(const short8*)(s1 + c * 512 + ((k * 2) ^ ((c & 7) << 4)));
            }
            short8 a = *(const short8*)(Wo + (w * 16 + n16) * L + k);
            #pragma unroll
            for (int ct = 0; ct < 4; ++ct) acc3[ct] = mfma16(a, bfr[ct], acc3[ct]);
        }
        int o0 = w * 16 + q * 4;
        f32x4 ob4 = *(const f32x4*)(ob + o0);
        float* obase = out + ((size_t)(b * Tn + t0)) * 64;
        #pragma unroll
        for (int ct = 0; ct < 4; ++ct) {
            int c = ct * 16 + n16;
            f32x4 v;
            #pragma unroll
            for (int j = 0; j < 4; ++j) v[j] = tanh_fast(acc3[ct][j] + ob4[j]);
            *(f32x4*)(obase + (size_t)c * 64 + o0) = v;
        }
    }
}

// ---------------------------------------------------------------------------
extern "C" void kernel_launch(void* const* d_in, const int* in_sizes, int n_in,
                              void* d_out, int out_size, void* d_ws, size_t ws_size,
                              hipStream_t stream)
{
    (void)in_sizes; (void)n_in; (void)out_size; (void)ws_size;
    const float* x      = (const float*)d_in[0];
    const float* emb_w  = (const float*)d_in[1];
    const float* emb_b  = (const float*)d_in[2];
    const float* filt_w = (const float*)d_in[3];
    const float* filt_b = (const float*)d_in[4];
    const float* gate_w = (const float*)d_in[5];
    const float* gate_b = (const float*)d_in[6];
    const float* res_w  = (const float*)d_in[7];
    const float* res_b  = (const float*)d_in[8];
    const float* skip_w = (const float*)d_in[9];
    const float* skip_b = (const float*)d_in[10];
    const float* fin1_w = (const float*)d_in[11];
    const float* fin1_b = (const float*)d_in[12];
    const float* fin2_w = (const float*)d_in[13];
    const float* fin2_b = (const float*)d_in[14];
    const float* out_w  = (const float*)d_in[15];
    const float* out_b  = (const float*)d_in[16];

    char* ws = (char*)d_ws;
    size_t off = 0;
    auto alloc = [&](size_t bytes) -> char* {
        char* p = ws + off;
        off += (bytes + 255) & ~(size_t)255;
        return p;
    };
    ushort_t* h_a = (ushort_t*)alloc((size_t)Bn * TP * L * 2);
    ushort_t* h_b = (ushort_t*)alloc((size_t)Bn * TP * L * 2);
    float*    fin = (float*)   alloc((size_t)Bn * Tn * L * 4);
    ushort_t* Wf  = (ushort_t*)alloc((size_t)NL * L * 2 * L * 2);
    ushort_t* Wg  = (ushort_t*)alloc((size_t)NL * L * 2 * L * 2);
    ushort_t* Wr  = (ushort_t*)alloc((size_t)NL * L * L * 2);
    ushort_t* Ws_ = (ushort_t*)alloc((size_t)(NL + 1) * L * L * 2);
    ushort_t* We  = (ushort_t*)alloc((size_t)L * IN_DIM * 2);
    ushort_t* W1  = (ushort_t*)alloc((size_t)L * L * 2);
    ushort_t* W2  = (ushort_t*)alloc((size_t)L * L * 2);
    ushort_t* Wo  = (ushort_t*)alloc((size_t)64 * L * 2);

    prep_kernel<<<512, 256, 0, stream>>>(filt_w, gate_w, res_w, skip_w, emb_w,
        fin1_w, fin2_w, out_w, Wf, Wg, Wr, Ws_, We, W1, W2, Wo, h_a, h_b);

    emb_kernel<<<1024, 512, 0, stream>>>(x, We, emb_b, Ws_, skip_b, h_a, fin);

    ushort_t* hin = h_a;
    ushort_t* hout = h_b;
    for (int i = 0; i < NL; ++i) {
        layer_kernel<<<1024, 512, 0, stream>>>(hin, hout, fin,
            Wf + (size_t)i * L * 2 * L, Wg + (size_t)i * L * 2 * L,
            Wr + (size_t)i * L * L, Ws_ + (size_t)(i + 1) * L * L,
            filt_b + i * L, gate_b + i * L, res_b + i * L, skip_b + (i + 1) * L,
            1 << i);
        ushort_t* t = hin; hin = hout; hout = t;
    }

    final_kernel<<<1024, 512, 0, stream>>>(fin, W1, fin1_b, W2, fin2_b,
        Wo, out_b, (float*)d_out);
}

// Round 5
// 1303.500 us; speedup vs baseline: 1.1222x; 1.1222x over previous
//
#include <hip/hip_runtime.h>
#include <hip/hip_bf16.h>

#define Bn 16
#define Tn 4096
#define IN_DIM 64
#define L 256
#define NL 10
#define PADROWS 512
#define TP (Tn + PADROWS)   // 4608
#define COLS 64

typedef __attribute__((ext_vector_type(8))) short short8;
typedef __attribute__((ext_vector_type(4))) float f32x4;
typedef unsigned short ushort_t;
typedef unsigned int uint_t;

__device__ inline ushort_t f2bf(float f) {
    uint_t u = __builtin_bit_cast(uint_t, f);
    u = u + 0x7fffu + ((u >> 16) & 1u);
    return (ushort_t)(u >> 16);
}

__device__ inline float fexp2f(float x) { return __builtin_amdgcn_exp2f(x); }
__device__ inline float frcpf(float x)  { return __builtin_amdgcn_rcpf(x); }
__device__ inline float tanh_fast(float x) {
    float e = fexp2f(x * 2.8853900817779268f);   // e^(2x)
    return 1.f - 2.f * frcpf(e + 1.f);
}
__device__ inline float sigm_fast(float x) {
    return frcpf(1.f + fexp2f(-1.4426950408889634f * x));
}

__device__ inline f32x4 mfma16(short8 a, short8 b, f32x4 c) {
    return __builtin_amdgcn_mfma_f32_16x16x32_bf16(a, b, c, 0, 0, 0);
}

__device__ inline void gld_lds16(const void* src, void* dst) {
    __builtin_amdgcn_global_load_lds(
        (const __attribute__((address_space(1))) void*)src,
        (__attribute__((address_space(3))) void*)dst, 16, 0, 0);
}

// bijective XCD-chunked swizzle for grid=1024 (1024 % 8 == 0, chunk=128)
__device__ inline int xcd_swz(int bid) {
    return (bid & 7) * 128 + (bid >> 3);
}

// A-tile slot swizzle: tile [256 r][4 slots of 16B]; logical q-chunk (k-offset
// q*8) of row r lives at slot q ^ aswz(r).
__device__ inline int aswz(int r) { return (r & 3) ^ ((r >> 2) & 3); }

__device__ inline short8 ldA(const char* wmat, int row, int q) {
    int s = q ^ aswz(row);
    return *(const short8*)(wmat + row * 64 + s * 16);
}

// stage one packed 16KB A-tile pair into LDS (linear dest, contiguous source)
__device__ inline void stageAp(char* wdst, const char* Wa, const char* Wb, int tid) {
    const int wbase = (tid >> 6) * 1024;   // wave base bytes (64 lanes * 16B)
    const int l16 = tid * 16;
    gld_lds16(Wa + l16,        wdst + wbase);
    gld_lds16(Wa + 8192 + l16, wdst + 8192 + wbase);
    gld_lds16(Wb + l16,        wdst + 16384 + wbase);
    gld_lds16(Wb + 8192 + l16, wdst + 24576 + wbase);
}

// ---------------------------------------------------------------------------
// prep: fp32 weights -> bf16, packed into per-K-step 16KB tiles with the
// A-slot swizzle baked in.  Also zero h pads.
// ---------------------------------------------------------------------------
__global__ void prep_kernel(
    const float* __restrict__ filt_w, const float* __restrict__ gate_w,
    const float* __restrict__ res_w,  const float* __restrict__ skip_w,
    const float* __restrict__ emb_w,  const float* __restrict__ fin1_w,
    const float* __restrict__ fin2_w, const float* __restrict__ out_w,
    ushort_t* __restrict__ Wfp, ushort_t* __restrict__ Wgp,
    ushort_t* __restrict__ Wrp, ushort_t* __restrict__ Wsp,
    ushort_t* __restrict__ Ws0, ushort_t* __restrict__ We,
    ushort_t* __restrict__ W1,  ushort_t* __restrict__ W2,
    ushort_t* __restrict__ Wo,
    ushort_t* __restrict__ h_a, ushort_t* __restrict__ h_b)
{
    const int stride = gridDim.x * blockDim.x;
    const int tid0 = blockIdx.x * blockDim.x + threadIdx.x;

    // filt/gate packed: [NL][16 steps][1024 slots][8 elems]
    // concat K: k<256 -> tap1 (unshifted h), k>=256 -> tap0 (shifted h)
    for (int idx = tid0; idx < NL * 16 * 1024 * 8; idx += stride) {
        int e = idx & 7;
        int j = (idx >> 3) & 1023;
        int t = (idx >> 13) & 15;
        int i = idx >> 17;
        int r = j >> 2, s = j & 3;
        int q = s ^ aswz(r);
        int k = t * 32 + q * 8 + e;
        int tap = (k < 256) ? 1 : 0;
        int kk = k & 255;
        int src = ((i * 256 + r) * 256 + kk) * 2 + tap;
        Wfp[idx] = f2bf(filt_w[src]);
        Wgp[idx] = f2bf(gate_w[src]);
    }
    // res / skip(1..10) packed: [NL][8 steps][1024 slots][8 elems]
    for (int idx = tid0; idx < NL * 8 * 1024 * 8; idx += stride) {
        int e = idx & 7;
        int j = (idx >> 3) & 1023;
        int t = (idx >> 13) & 7;
        int i = idx >> 16;
        int r = j >> 2;
        int q = (j & 3) ^ aswz(r);
        int k = t * 32 + q * 8 + e;
        Wrp[idx] = f2bf(res_w[(i * 256 + r) * 256 + k]);
        Wsp[idx] = f2bf(skip_w[((i + 1) * 256 + r) * 256 + k]);
    }
    // row-major small weights
    for (int idx = tid0; idx < L * L; idx += stride) {
        Ws0[idx] = f2bf(skip_w[idx]);
        W1[idx] = f2bf(fin1_w[idx]);
        W2[idx] = f2bf(fin2_w[idx]);
    }
    for (int idx = tid0; idx < L * IN_DIM; idx += stride) We[idx] = f2bf(emb_w[idx]);
    for (int idx = tid0; idx < 64 * L; idx += stride)     Wo[idx] = f2bf(out_w[idx]);
    // zero the 512-row time pads of both h buffers
    for (int idx = tid0; idx < Bn * PADROWS * L; idx += stride) {
        int bb = idx >> 17;            // 512*256 = 1<<17
        int r = idx & 131071;
        size_t off = (size_t)bb * TP * L + r;
        h_a[off] = 0;
        h_b[off] = 0;
    }
}

// ---------------------------------------------------------------------------
// embedding: h0 = relu(We @ x^T + eb); final = Ws0 @ h0 + sb0
// ---------------------------------------------------------------------------
__global__ __launch_bounds__(512, 4) void emb_kernel(
    const float* __restrict__ x,
    const ushort_t* __restrict__ We, const float* __restrict__ eb,
    const ushort_t* __restrict__ Ws0, const float* __restrict__ sb0,
    ushort_t* __restrict__ h_out, float* __restrict__ fin)
{
    __shared__ __align__(16) char gt[32 * 1024];   // [64][256] bf16, chunk-swizzled

    const int tid = threadIdx.x;
    const int w = tid >> 6;
    const int ln = tid & 63;
    const int q = ln >> 4;
    const int n16 = ln & 15;
    const int lid = xcd_swz(blockIdx.x);
    const int b = lid >> 6;
    const int t0 = (lid & 63) * COLS;
    const int row0 = w * 32;

    f32x4 acc[2][4];
    #pragma unroll
    for (int rt = 0; rt < 2; ++rt)
        #pragma unroll
        for (int ct = 0; ct < 4; ++ct) acc[rt][ct] = (f32x4){0.f, 0.f, 0.f, 0.f};

    #pragma unroll
    for (int ks = 0; ks < 2; ++ks) {
        const int k = ks * 32 + q * 8;
        short8 bfr[4];
        #pragma unroll
        for (int ct = 0; ct < 4; ++ct) {
            int c = ct * 16 + n16;
            const float* xp = x + ((size_t)(b * Tn + t0 + c)) * IN_DIM + k;
            f32x4 x0 = *(const f32x4*)xp;
            f32x4 x1 = *(const f32x4*)(xp + 4);
            short8 v;
            v[0] = (short)f2bf(x0[0]); v[1] = (short)f2bf(x0[1]);
            v[2] = (short)f2bf(x0[2]); v[3] = (short)f2bf(x0[3]);
            v[4] = (short)f2bf(x1[0]); v[5] = (short)f2bf(x1[1]);
            v[6] = (short)f2bf(x1[2]); v[7] = (short)f2bf(x1[3]);
            bfr[ct] = v;
        }
        #pragma unroll
        for (int rt = 0; rt < 2; ++rt) {
            int row = row0 + rt * 16 + n16;
            short8 a = *(const short8*)(We + row * IN_DIM + k);
            #pragma unroll
            for (int ct = 0; ct < 4; ++ct)
                acc[rt][ct] = mfma16(a, bfr[ct], acc[rt][ct]);
        }
    }

    // epilogue: h0 = relu(acc + eb) -> global h + LDS gt
    ushort_t* hob = h_out + ((size_t)(b * TP + PADROWS + t0)) * L;
    #pragma unroll
    for (int rt = 0; rt < 2; ++rt) {
        int i0 = row0 + rt * 16 + q * 4;
        f32x4 eb4 = *(const f32x4*)(eb + i0);
        #pragma unroll
        for (int ct = 0; ct < 4; ++ct) {
            int c = ct * 16 + n16;
            f32x4 h0 = acc[rt][ct] + eb4;
            float v0 = fmaxf(h0[0], 0.f), v1 = fmaxf(h0[1], 0.f);
            float v2 = fmaxf(h0[2], 0.f), v3 = fmaxf(h0[3], 0.f);
            uint_t lo = (uint_t)f2bf(v0) | ((uint_t)f2bf(v1) << 16);
            uint_t hi = (uint_t)f2bf(v2) | ((uint_t)f2bf(v3) << 16);
            *(uint2*)(hob + (size_t)c * L + i0) = make_uint2(lo, hi);
            int byt = c * 512 + ((i0 * 2) ^ ((c & 7) << 4));
            *(uint2*)(gt + byt) = make_uint2(lo, hi);
        }
    }
    __syncthreads();

    // skip0 GEMM over gt
    f32x4 accs[2][4];
    #pragma unroll
    for (int rt = 0; rt < 2; ++rt)
        #pragma unroll
        for (int ct = 0; ct < 4; ++ct) accs[rt][ct] = (f32x4){0.f, 0.f, 0.f, 0.f};

    for (int ks = 0; ks < 8; ++ks) {
        const int k = ks * 32 + q * 8;
        short8 bg[4];
        #pragma unroll
        for (int ct = 0; ct < 4; ++ct) {
            int c = ct * 16 + n16;
            bg[ct] = *(const short8*)(gt + c * 512 + ((k * 2) ^ ((c & 7) << 4)));
        }
        #pragma unroll
        for (int rt = 0; rt < 2; ++rt) {
            int row = row0 + rt * 16 + n16;
            short8 a = *(const short8*)(Ws0 + row * L + k);
            #pragma unroll
            for (int ct = 0; ct < 4; ++ct)
                accs[rt][ct] = mfma16(a, bg[ct], accs[rt][ct]);
        }
    }
    float* fob = fin + ((size_t)(b * Tn + t0)) * L;
    #pragma unroll
    for (int rt = 0; rt < 2; ++rt) {
        int i0 = row0 + rt * 16 + q * 4;
        f32x4 sb4 = *(const f32x4*)(sb0 + i0);
        #pragma unroll
        for (int ct = 0; ct < 4; ++ct) {
            int c = ct * 16 + n16;
            *(f32x4*)(fob + (size_t)c * L + i0) = accs[rt][ct] + sb4;  // first write
        }
    }
}

// ---------------------------------------------------------------------------
// one WaveNet layer.  LDS: hh 64KB (resident B) + wb 2x32KB (streamed A dbuf).
//   hh row c (1024B, 64 16B-chunks, physical chunk p holds logical chunk
//   p ^ (c&7)):
//     logical chunks  0..31 : h[t0+c][ch]           (res + filt/gate tap1)
//     logical chunks 32..63 : h[t0+c-d][ch]  phase1 (filt/gate tap0)
//                             gated[c][ch]   phase2 (overwritten after barrier)
//   wb[buf]: two 16KB packed A-tiles (f|g in ph1, s|r in ph2), staged via
//   global_load_lds from prep-packed contiguous tiles; one barrier per K-step.
// ---------------------------------------------------------------------------
__global__ __launch_bounds__(512, 2) void layer_kernel(
    const ushort_t* __restrict__ h_in, ushort_t* __restrict__ h_out,
    float* __restrict__ fin,
    const char* __restrict__ WfL, const char* __restrict__ WgL,
    const char* __restrict__ WrL, const char* __restrict__ WsL,
    const float* __restrict__ fb_, const float* __restrict__ gb_,
    const float* __restrict__ rb_, const float* __restrict__ sb_,
    int d)
{
    __shared__ __align__(16) char hh[64 * 1024];
    __shared__ __align__(16) char wb2[2][32 * 1024];

    const int tid = threadIdx.x;
    const int w = tid >> 6;
    const int ln = tid & 63;
    const int q = ln >> 4;
    const int n16 = ln & 15;
    const int lid = xcd_swz(blockIdx.x);
    const int b = lid >> 6;
    const int t0 = (lid & 63) * COLS;
    const int row0 = w * 32;

    // ---- prologue: stage hh (pre-swizzled source, linear dest) + A-tile 0
    const ushort_t* hbase = h_in + ((size_t)(b * TP + PADROWS + t0)) * L;
    #pragma unroll
    for (int it = 0; it < 8; ++it) {
        int c = it * 8 + w;                 // wave-uniform row
        int chunk = ln ^ (c & 7);           // pre-swizzled logical 16B-chunk
        int sh = (chunk >= 32) ? d : 0;
        const ushort_t* src = hbase + ((long)c - sh) * L + (chunk & 31) * 8;
        gld_lds16(src, hh + c * 1024);
    }
    stageAp(wb2[0], WfL, WgL, tid);
    __syncthreads();

    // ---- phase 1: filt & gate (K=512 concat), 16 K-steps, A dbuf-streamed
    f32x4 accf[2][4], accg[2][4];
    #pragma unroll
    for (int rt = 0; rt < 2; ++rt)
        #pragma unroll
        for (int ct = 0; ct < 4; ++ct) {
            accf[rt][ct] = (f32x4){0.f, 0.f, 0.f, 0.f};
            accg[rt][ct] = (f32x4){0.f, 0.f, 0.f, 0.f};
        }

    int buf = 0;
    for (int st = 0; st < 16; ++st) {
        if (st < 15)
            stageAp(wb2[buf ^ 1], WfL + (st + 1) * 16384, WgL + (st + 1) * 16384, tid);
        const int kq = st * 32 + q * 8;
        short8 bfr[4];
        #pragma unroll
        for (int ct = 0; ct < 4; ++ct) {
            int c = ct * 16 + n16;
            bfr[ct] = *(const short8*)(hh + c * 1024 + ((kq * 2) ^ ((c & 7) << 4)));
        }
        const char* wf = wb2[buf];
        const char* wg = wb2[buf] + 16384;
        short8 af0 = ldA(wf, row0 + n16, q);
        short8 af1 = ldA(wf, row0 + 16 + n16, q);
        short8 ag0 = ldA(wg, row0 + n16, q);
        short8 ag1 = ldA(wg, row0 + 16 + n16, q);
        #pragma unroll
        for (int ct = 0; ct < 4; ++ct) {
            accf[0][ct] = mfma16(af0, bfr[ct], accf[0][ct]);
            accf[1][ct] = mfma16(af1, bfr[ct], accf[1][ct]);
            accg[0][ct] = mfma16(ag0, bfr[ct], accg[0][ct]);
            accg[1][ct] = mfma16(ag1, bfr[ct], accg[1][ct]);
        }
        __syncthreads();
        buf ^= 1;
    }
    // buf == 0 here; wb2[0] is free (last read at st=14, barrier passed)
    stageAp(wb2[buf], WsL, WrL, tid);   // ph2 tile 0 flies during activation

    // ---- epilogue 1: gated = tanh(f+fb)*sigmoid(g+gb) -> hh logical 32..63
    #pragma unroll
    for (int rt = 0; rt < 2; ++rt) {
        int i0 = row0 + rt * 16 + q * 4;
        f32x4 fb4 = *(const f32x4*)(fb_ + i0);
        f32x4 gb4 = *(const f32x4*)(gb_ + i0);
        #pragma unroll
        for (int ct = 0; ct < 4; ++ct) {
            int c = ct * 16 + n16;
            uint_t pk[2];
            #pragma unroll
            for (int h2 = 0; h2 < 2; ++h2) {
                float v0 = tanh_fast(accf[rt][ct][h2 * 2] + fb4[h2 * 2]) *
                           sigm_fast(accg[rt][ct][h2 * 2] + gb4[h2 * 2]);
                float v1 = tanh_fast(accf[rt][ct][h2 * 2 + 1] + fb4[h2 * 2 + 1]) *
                           sigm_fast(accg[rt][ct][h2 * 2 + 1] + gb4[h2 * 2 + 1]);
                pk[h2] = (uint_t)f2bf(v0) | ((uint_t)f2bf(v1) << 16);
            }
            int byt = c * 1024 + ((512 + i0 * 2) ^ ((c & 7) << 4));
            *(uint2*)(hh + byt) = make_uint2(pk[0], pk[1]);
        }
    }
    __syncthreads();

    // ---- phase 2: skip (gated, logical bytes 512+2k) & res (bytes 2k)
    f32x4 accs[2][4], accr[2][4];
    #pragma unroll
    for (int rt = 0; rt < 2; ++rt)
        #pragma unroll
        for (int ct = 0; ct < 4; ++ct) {
            accs[rt][ct] = (f32x4){0.f, 0.f, 0.f, 0.f};
            accr[rt][ct] = (f32x4){0.f, 0.f, 0.f, 0.f};
        }

    for (int st = 0; st < 8; ++st) {
        if (st < 7)
            stageAp(wb2[buf ^ 1], WsL + (st + 1) * 16384, WrL + (st + 1) * 16384, tid);
        const int kq = st * 32 + q * 8;
        short8 bg[4], bh[4];
        #pragma unroll
        for (int ct = 0; ct < 4; ++ct) {
            int c = ct * 16 + n16;
            // FIX (R4 bug): logical byte is 512 + kq*2, NOT (512+kq)*2
            bg[ct] = *(const short8*)(hh + c * 1024 +
                                      ((512 + kq * 2) ^ ((c & 7) << 4)));
            bh[ct] = *(const short8*)(hh + c * 1024 + ((kq * 2) ^ ((c & 7) << 4)));
        }
        const char* ws = wb2[buf];
        const char* wr = wb2[buf] + 16384;
        short8 as0 = ldA(ws, row0 + n16, q);
        short8 as1 = ldA(ws, row0 + 16 + n16, q);
        short8 ar0 = ldA(wr, row0 + n16, q);
        short8 ar1 = ldA(wr, row0 + 16 + n16, q);
        #pragma unroll
        for (int ct = 0; ct < 4; ++ct) {
            accs[0][ct] = mfma16(as0, bg[ct], accs[0][ct]);
            accs[1][ct] = mfma16(as1, bg[ct], accs[1][ct]);
            accr[0][ct] = mfma16(ar0, bh[ct], accr[0][ct]);
            accr[1][ct] = mfma16(ar1, bh[ct], accr[1][ct]);
        }
        __syncthreads();
        buf ^= 1;
    }

    // ---- epilogue 2: h' = skip+res (bf16), final += skip (fp32 RMW)
    ushort_t* hob = h_out + ((size_t)(b * TP + PADROWS + t0)) * L;
    float* fob = fin + ((size_t)(b * Tn + t0)) * L;
    #pragma unroll
    for (int rt = 0; rt < 2; ++rt) {
        int i0 = row0 + rt * 16 + q * 4;
        f32x4 sb4 = *(const f32x4*)(sb_ + i0);
        f32x4 rb4 = *(const f32x4*)(rb_ + i0);
        #pragma unroll
        for (int ct = 0; ct < 4; ++ct) {
            int c = ct * 16 + n16;
            f32x4 sk = accs[rt][ct] + sb4;
            f32x4 hn = sk + accr[rt][ct] + rb4;
            uint_t lo = (uint_t)f2bf(hn[0]) | ((uint_t)f2bf(hn[1]) << 16);
            uint_t hi = (uint_t)f2bf(hn[2]) | ((uint_t)f2bf(hn[3]) << 16);
            *(uint2*)(hob + (size_t)c * L + i0) = make_uint2(lo, hi);
            f32x4* fp = (f32x4*)(fob + (size_t)c * L + i0);
            *fp = *fp + sk;
        }
    }
}

// ---------------------------------------------------------------------------
// head: relu->fin1->relu->fin2->out_w->tanh
// ---------------------------------------------------------------------------
__global__ __launch_bounds__(512, 4) void final_kernel(
    const float* __restrict__ fin,
    const ushort_t* __restrict__ W1, const float* __restrict__ b1,
    const ushort_t* __restrict__ W2, const float* __restrict__ b2,
    const ushort_t* __restrict__ Wo, const float* __restrict__ ob,
    float* __restrict__ out)
{
    __shared__ __align__(16) char s1[32 * 1024];
    __shared__ __align__(16) char s2[32 * 1024];

    const int tid = threadIdx.x;
    const int w = tid >> 6;
    const int ln = tid & 63;
    const int q = ln >> 4;
    const int n16 = ln & 15;
    const int lid = xcd_swz(blockIdx.x);
    const int b = lid >> 6;
    const int t0 = (lid & 63) * COLS;
    const int row0 = w * 32;

    // stage s1 = bf16(relu(final))
    {
        int c = tid & 63;
        int kg = tid >> 6;
        const float* fp = fin + ((size_t)(b * Tn + t0 + c)) * L + kg * 32;
        #pragma unroll
        for (int j = 0; j < 8; ++j) {
            f32x4 v = *(const f32x4*)(fp + j * 4);
            uint_t lo = (uint_t)f2bf(fmaxf(v[0], 0.f)) | ((uint_t)f2bf(fmaxf(v[1], 0.f)) << 16);
            uint_t hi = (uint_t)f2bf(fmaxf(v[2], 0.f)) | ((uint_t)f2bf(fmaxf(v[3], 0.f)) << 16);
            int kk = kg * 32 + j * 4;
            *(uint2*)(s1 + c * 512 + ((kk * 2) ^ ((c & 7) << 4))) = make_uint2(lo, hi);
        }
    }
    __syncthreads();

    // GEMM1: z1 = W1 @ s1; relu -> s2
    f32x4 acc[2][4];
    #pragma unroll
    for (int rt = 0; rt < 2; ++rt)
        #pragma unroll
        for (int ct = 0; ct < 4; ++ct) acc[rt][ct] = (f32x4){0.f, 0.f, 0.f, 0.f};
    for (int ks = 0; ks < 8; ++ks) {
        const int k = ks * 32 + q * 8;
        short8 bfr[4];
        #pragma unroll
        for (int ct = 0; ct < 4; ++ct) {
            int c = ct * 16 + n16;
            bfr[ct] = *(const short8*)(s1 + c * 512 + ((k * 2) ^ ((c & 7) << 4)));
        }
        #pragma unroll
        for (int rt = 0; rt < 2; ++rt) {
            int row = row0 + rt * 16 + n16;
            short8 a = *(const short8*)(W1 + row * L + k);
            #pragma unroll
            for (int ct = 0; ct < 4; ++ct) acc[rt][ct] = mfma16(a, bfr[ct], acc[rt][ct]);
        }
    }
    #pragma unroll
    for (int rt = 0; rt < 2; ++rt) {
        int i0 = row0 + rt * 16 + q * 4;
        f32x4 bb = *(const f32x4*)(b1 + i0);
        #pragma unroll
        for (int ct = 0; ct < 4; ++ct) {
            int c = ct * 16 + n16;
            f32x4 z = acc[rt][ct] + bb;
            uint_t lo = (uint_t)f2bf(fmaxf(z[0], 0.f)) | ((uint_t)f2bf(fmaxf(z[1], 0.f)) << 16);
            uint_t hi = (uint_t)f2bf(fmaxf(z[2], 0.f)) | ((uint_t)f2bf(fmaxf(z[3], 0.f)) << 16);
            *(uint2*)(s2 + c * 512 + ((i0 * 2) ^ ((c & 7) << 4))) = make_uint2(lo, hi);
        }
    }
    __syncthreads();

    // GEMM2: z2 = W2 @ s2 (no relu) -> s1
    #pragma unroll
    for (int rt = 0; rt < 2; ++rt)
        #pragma unroll
        for (int ct = 0; ct < 4; ++ct) acc[rt][ct] = (f32x4){0.f, 0.f, 0.f, 0.f};
    for (int ks = 0; ks < 8; ++ks) {
        const int k = ks * 32 + q * 8;
        short8 bfr[4];
        #pragma unroll
        for (int ct = 0; ct < 4; ++ct) {
            int c = ct * 16 + n16;
            bfr[ct] = *(const short8*)(s2 + c * 512 + ((k * 2) ^ ((c & 7) << 4)));
        }
        #pragma unroll
        for (int rt = 0; rt < 2; ++rt) {
            int row = row0 + rt * 16 + n16;
            short8 a = *(const short8*)(W2 + row * L + k);
            #pragma unroll
            for (int ct = 0; ct < 4; ++ct) acc[rt][ct] = mfma16(a, bfr[ct], acc[rt][ct]);
        }
    }
    #pragma unroll
    for (int rt = 0; rt < 2; ++rt) {
        int i0 = row0 + rt * 16 + q * 4;
        f32x4 bb = *(const f32x4*)(b2 + i0);
        #pragma unroll
        for (int ct = 0; ct < 4; ++ct) {
            int c = ct * 16 + n16;
            f32x4 z = acc[rt][ct] + bb;
            uint_t lo = (uint_t)f2bf(z[0]) | ((uint_t)f2bf(z[1]) << 16);
            uint_t hi = (uint_t)f2bf(z[2]) | ((uint_t)f2bf(z[3]) << 16);
            *(uint2*)(s1 + c * 512 + ((i0 * 2) ^ ((c & 7) << 4))) = make_uint2(lo, hi);
        }
    }
    __syncthreads();

    // GEMM3: out = tanh(Wo @ z2 + ob)  (M=64, waves 0..3)
    if (w < 4) {
        f32x4 acc3[4];
        #pragma unroll
        for (int ct = 0; ct < 4; ++ct) acc3[ct] = (f32x4){0.f, 0.f, 0.f, 0.f};
        for (int ks = 0; ks < 8; ++ks) {
            const int k = ks * 32 + q * 8;
            short8 bfr[4];
            #pragma unroll
            for (int ct = 0; ct < 4; ++ct) {
                int c = ct * 16 + n16;
                bfr[ct] = *(const short8*)(s1 + c * 512 + ((k * 2) ^ ((c & 7) << 4)));
            }
            short8 a = *(const short8*)(Wo + (w * 16 + n16) * L + k);
            #pragma unroll
            for (int ct = 0; ct < 4; ++ct) acc3[ct] = mfma16(a, bfr[ct], acc3[ct]);
        }
        int o0 = w * 16 + q * 4;
        f32x4 ob4 = *(const f32x4*)(ob + o0);
        float* obase = out + ((size_t)(b * Tn + t0)) * 64;
        #pragma unroll
        for (int ct = 0; ct < 4; ++ct) {
            int c = ct * 16 + n16;
            f32x4 v;
            #pragma unroll
            for (int j = 0; j < 4; ++j) v[j] = tanh_fast(acc3[ct][j] + ob4[j]);
            *(f32x4*)(obase + (size_t)c * 64 + o0) = v;
        }
    }
}

// ---------------------------------------------------------------------------
extern "C" void kernel_launch(void* const* d_in, const int* in_sizes, int n_in,
                              void* d_out, int out_size, void* d_ws, size_t ws_size,
                              hipStream_t stream)
{
    (void)in_sizes; (void)n_in; (void)out_size; (void)ws_size;
    const float* x      = (const float*)d_in[0];
    const float* emb_w  = (const float*)d_in[1];
    const float* emb_b  = (const float*)d_in[2];
    const float* filt_w = (const float*)d_in[3];
    const float* filt_b = (const float*)d_in[4];
    const float* gate_w = (const float*)d_in[5];
    const float* gate_b = (const float*)d_in[6];
    const float* res_w  = (const float*)d_in[7];
    const float* res_b  = (const float*)d_in[8];
    const float* skip_w = (const float*)d_in[9];
    const float* skip_b = (const float*)d_in[10];
    const float* fin1_w = (const float*)d_in[11];
    const float* fin1_b = (const float*)d_in[12];
    const float* fin2_w = (const float*)d_in[13];
    const float* fin2_b = (const float*)d_in[14];
    const float* out_w  = (const float*)d_in[15];
    const float* out_b  = (const float*)d_in[16];

    char* ws = (char*)d_ws;
    size_t off = 0;
    auto alloc = [&](size_t bytes) -> char* {
        char* p = ws + off;
        off += (bytes + 255) & ~(size_t)255;
        return p;
    };
    ushort_t* h_a = (ushort_t*)alloc((size_t)Bn * TP * L * 2);
    ushort_t* h_b = (ushort_t*)alloc((size_t)Bn * TP * L * 2);
    float*    fin = (float*)   alloc((size_t)Bn * Tn * L * 4);
    ushort_t* Wfp = (ushort_t*)alloc((size_t)NL * 16 * 1024 * 8 * 2);
    ushort_t* Wgp = (ushort_t*)alloc((size_t)NL * 16 * 1024 * 8 * 2);
    ushort_t* Wrp = (ushort_t*)alloc((size_t)NL * 8 * 1024 * 8 * 2);
    ushort_t* Wsp = (ushort_t*)alloc((size_t)NL * 8 * 1024 * 8 * 2);
    ushort_t* Ws0 = (ushort_t*)alloc((size_t)L * L * 2);
    ushort_t* We  = (ushort_t*)alloc((size_t)L * IN_DIM * 2);
    ushort_t* W1  = (ushort_t*)alloc((size_t)L * L * 2);
    ushort_t* W2  = (ushort_t*)alloc((size_t)L * L * 2);
    ushort_t* Wo  = (ushort_t*)alloc((size_t)64 * L * 2);

    prep_kernel<<<512, 256, 0, stream>>>(filt_w, gate_w, res_w, skip_w, emb_w,
        fin1_w, fin2_w, out_w, Wfp, Wgp, Wrp, Wsp, Ws0, We, W1, W2, Wo, h_a, h_b);

    emb_kernel<<<1024, 512, 0, stream>>>(x, We, emb_b, Ws0, skip_b, h_a, fin);

    ushort_t* hin = h_a;
    ushort_t* hout = h_b;
    for (int i = 0; i < NL; ++i) {
        layer_kernel<<<1024, 512, 0, stream>>>(hin, hout, fin,
            (const char*)Wfp + (size_t)i * 16 * 16384,
            (const char*)Wgp + (size_t)i * 16 * 16384,
            (const char*)Wrp + (size_t)i * 8 * 16384,
            (const char*)Wsp + (size_t)i * 8 * 16384,
            filt_b + i * L, gate_b + i * L, res_b + i * L, skip_b + (i + 1) * L,
            1 << i);
        ushort_t* t = hin; hin = hout; hout = t;
    }

    final_kernel<<<1024, 512, 0, stream>>>(fin, W1, fin1_b, W2, fin2_b,
        Wo, out_b, (float*)d_out);
}

// Round 6
// 1026.631 us; speedup vs baseline: 1.4249x; 1.2697x over previous
//
#include <hip/hip_runtime.h>
#include <hip/hip_bf16.h>

#define Bn 16
#define Tn 4096
#define IN_DIM 64
#define L 256
#define NL 10
#define PADROWS 512
#define TP (Tn + PADROWS)   // 4608
#define COLS 64

typedef __attribute__((ext_vector_type(8))) short short8;
typedef __attribute__((ext_vector_type(4))) float f32x4;
typedef unsigned short ushort_t;
typedef unsigned int uint_t;

__device__ inline ushort_t f2bf(float f) {
    uint_t u = __builtin_bit_cast(uint_t, f);
    u = u + 0x7fffu + ((u >> 16) & 1u);
    return (ushort_t)(u >> 16);
}

__device__ inline float fexp2f(float x) { return __builtin_amdgcn_exp2f(x); }
__device__ inline float frcpf(float x)  { return __builtin_amdgcn_rcpf(x); }
__device__ inline float tanh_fast(float x) {
    float e = fexp2f(x * 2.8853900817779268f);   // e^(2x)
    return 1.f - 2.f * frcpf(e + 1.f);
}
__device__ inline float sigm_fast(float x) {
    return frcpf(1.f + fexp2f(-1.4426950408889634f * x));
}

__device__ inline f32x4 mfma16(short8 a, short8 b, f32x4 c) {
    return __builtin_amdgcn_mfma_f32_16x16x32_bf16(a, b, c, 0, 0, 0);
}

__device__ inline void gld_lds16(const void* src, void* dst) {
    __builtin_amdgcn_global_load_lds(
        (const __attribute__((address_space(1))) void*)src,
        (__attribute__((address_space(3))) void*)dst, 16, 0, 0);
}

// bijective XCD-chunked swizzle for grid=1024 (1024 % 8 == 0, chunk=128)
__device__ inline int xcd_swz(int bid) {
    return (bid & 7) * 128 + (bid >> 3);
}

// ---------------------------------------------------------------------------
// prep: fp32 weights -> bf16, packed lane-linear per K-step:
//   [steps][16 rgrp][4 q][16 r][8 e]  (1 KB per (step,rgrp); wave w step t
//   fragment rt lives at  t*16384 + (2w+rt)*1024 + lane*16  -- fully coalesced)
// Also zero h pads.
// ---------------------------------------------------------------------------
__global__ void prep_kernel(
    const float* __restrict__ filt_w, const float* __restrict__ gate_w,
    const float* __restrict__ res_w,  const float* __restrict__ skip_w,
    const float* __restrict__ emb_w,  const float* __restrict__ fin1_w,
    const float* __restrict__ fin2_w, const float* __restrict__ out_w,
    ushort_t* __restrict__ Wfp, ushort_t* __restrict__ Wgp,
    ushort_t* __restrict__ Wrp, ushort_t* __restrict__ Wsp,
    ushort_t* __restrict__ Ws0, ushort_t* __restrict__ We,
    ushort_t* __restrict__ W1,  ushort_t* __restrict__ W2,
    ushort_t* __restrict__ Wo,
    ushort_t* __restrict__ h_a, ushort_t* __restrict__ h_b)
{
    const int stride = gridDim.x * blockDim.x;
    const int tid0 = blockIdx.x * blockDim.x + threadIdx.x;

    // filt/gate packed: [NL][16 steps][16 rg][4 q][16 r][8 e]
    // concat K: k<256 -> tap1 (unshifted h), k>=256 -> tap0 (shifted h)
    for (int idx = tid0; idx < NL * 16 * 1024 * 8; idx += stride) {
        int e  = idx & 7;
        int r  = (idx >> 3) & 15;
        int qq = (idx >> 7) & 3;
        int rg = (idx >> 9) & 15;
        int t  = (idx >> 13) & 15;
        int i  = idx >> 17;
        int row = rg * 16 + r;
        int k = t * 32 + qq * 8 + e;
        int tap = (k < 256) ? 1 : 0;
        int kk = k & 255;
        int src = ((i * 256 + row) * 256 + kk) * 2 + tap;
        Wfp[idx] = f2bf(filt_w[src]);
        Wgp[idx] = f2bf(gate_w[src]);
    }
    // res / skip(1..10) packed: [NL][8 steps][16 rg][4 q][16 r][8 e]
    for (int idx = tid0; idx < NL * 8 * 1024 * 8; idx += stride) {
        int e  = idx & 7;
        int r  = (idx >> 3) & 15;
        int qq = (idx >> 7) & 3;
        int rg = (idx >> 9) & 15;
        int t  = (idx >> 13) & 7;
        int i  = idx >> 16;
        int row = rg * 16 + r;
        int k = t * 32 + qq * 8 + e;
        Wrp[idx] = f2bf(res_w[(i * 256 + row) * 256 + k]);
        Wsp[idx] = f2bf(skip_w[((i + 1) * 256 + row) * 256 + k]);
    }
    // row-major small weights
    for (int idx = tid0; idx < L * L; idx += stride) {
        Ws0[idx] = f2bf(skip_w[idx]);
        W1[idx] = f2bf(fin1_w[idx]);
        W2[idx] = f2bf(fin2_w[idx]);
    }
    for (int idx = tid0; idx < L * IN_DIM; idx += stride) We[idx] = f2bf(emb_w[idx]);
    for (int idx = tid0; idx < 64 * L; idx += stride)     Wo[idx] = f2bf(out_w[idx]);
    // zero the 512-row time pads of both h buffers
    for (int idx = tid0; idx < Bn * PADROWS * L; idx += stride) {
        int bb = idx >> 17;            // 512*256 = 1<<17
        int r = idx & 131071;
        size_t off = (size_t)bb * TP * L + r;
        h_a[off] = 0;
        h_b[off] = 0;
    }
}

// ---------------------------------------------------------------------------
// embedding: h0 = relu(We @ x^T + eb); final = Ws0 @ h0 + sb0
// ---------------------------------------------------------------------------
__global__ __launch_bounds__(512, 4) void emb_kernel(
    const float* __restrict__ x,
    const ushort_t* __restrict__ We, const float* __restrict__ eb,
    const ushort_t* __restrict__ Ws0, const float* __restrict__ sb0,
    ushort_t* __restrict__ h_out, float* __restrict__ fin)
{
    __shared__ __align__(16) char gt[32 * 1024];   // [64][256] bf16, chunk-swizzled

    const int tid = threadIdx.x;
    const int w = tid >> 6;
    const int ln = tid & 63;
    const int q = ln >> 4;
    const int n16 = ln & 15;
    const int lid = xcd_swz(blockIdx.x);
    const int b = lid >> 6;
    const int t0 = (lid & 63) * COLS;
    const int row0 = w * 32;

    f32x4 acc[2][4];
    #pragma unroll
    for (int rt = 0; rt < 2; ++rt)
        #pragma unroll
        for (int ct = 0; ct < 4; ++ct) acc[rt][ct] = (f32x4){0.f, 0.f, 0.f, 0.f};

    #pragma unroll
    for (int ks = 0; ks < 2; ++ks) {
        const int k = ks * 32 + q * 8;
        short8 bfr[4];
        #pragma unroll
        for (int ct = 0; ct < 4; ++ct) {
            int c = ct * 16 + n16;
            const float* xp = x + ((size_t)(b * Tn + t0 + c)) * IN_DIM + k;
            f32x4 x0 = *(const f32x4*)xp;
            f32x4 x1 = *(const f32x4*)(xp + 4);
            short8 v;
            v[0] = (short)f2bf(x0[0]); v[1] = (short)f2bf(x0[1]);
            v[2] = (short)f2bf(x0[2]); v[3] = (short)f2bf(x0[3]);
            v[4] = (short)f2bf(x1[0]); v[5] = (short)f2bf(x1[1]);
            v[6] = (short)f2bf(x1[2]); v[7] = (short)f2bf(x1[3]);
            bfr[ct] = v;
        }
        #pragma unroll
        for (int rt = 0; rt < 2; ++rt) {
            int row = row0 + rt * 16 + n16;
            short8 a = *(const short8*)(We + row * IN_DIM + k);
            #pragma unroll
            for (int ct = 0; ct < 4; ++ct)
                acc[rt][ct] = mfma16(a, bfr[ct], acc[rt][ct]);
        }
    }

    // epilogue: h0 = relu(acc + eb) -> global h + LDS gt
    ushort_t* hob = h_out + ((size_t)(b * TP + PADROWS + t0)) * L;
    #pragma unroll
    for (int rt = 0; rt < 2; ++rt) {
        int i0 = row0 + rt * 16 + q * 4;
        f32x4 eb4 = *(const f32x4*)(eb + i0);
        #pragma unroll
        for (int ct = 0; ct < 4; ++ct) {
            int c = ct * 16 + n16;
            f32x4 h0 = acc[rt][ct] + eb4;
            float v0 = fmaxf(h0[0], 0.f), v1 = fmaxf(h0[1], 0.f);
            float v2 = fmaxf(h0[2], 0.f), v3 = fmaxf(h0[3], 0.f);
            uint_t lo = (uint_t)f2bf(v0) | ((uint_t)f2bf(v1) << 16);
            uint_t hi = (uint_t)f2bf(v2) | ((uint_t)f2bf(v3) << 16);
            *(uint2*)(hob + (size_t)c * L + i0) = make_uint2(lo, hi);
            int byt = c * 512 + ((i0 * 2) ^ ((c & 7) << 4));
            *(uint2*)(gt + byt) = make_uint2(lo, hi);
        }
    }
    __syncthreads();

    // skip0 GEMM over gt
    f32x4 accs[2][4];
    #pragma unroll
    for (int rt = 0; rt < 2; ++rt)
        #pragma unroll
        for (int ct = 0; ct < 4; ++ct) accs[rt][ct] = (f32x4){0.f, 0.f, 0.f, 0.f};

    for (int ks = 0; ks < 8; ++ks) {
        const int k = ks * 32 + q * 8;
        short8 bg[4];
        #pragma unroll
        for (int ct = 0; ct < 4; ++ct) {
            int c = ct * 16 + n16;
            bg[ct] = *(const short8*)(gt + c * 512 + ((k * 2) ^ ((c & 7) << 4)));
        }
        #pragma unroll
        for (int rt = 0; rt < 2; ++rt) {
            int row = row0 + rt * 16 + n16;
            short8 a = *(const short8*)(Ws0 + row * L + k);
            #pragma unroll
            for (int ct = 0; ct < 4; ++ct)
                accs[rt][ct] = mfma16(a, bg[ct], accs[rt][ct]);
        }
    }
    float* fob = fin + ((size_t)(b * Tn + t0)) * L;
    #pragma unroll
    for (int rt = 0; rt < 2; ++rt) {
        int i0 = row0 + rt * 16 + q * 4;
        f32x4 sb4 = *(const f32x4*)(sb0 + i0);
        #pragma unroll
        for (int ct = 0; ct < 4; ++ct) {
            int c = ct * 16 + n16;
            *(f32x4*)(fob + (size_t)c * L + i0) = accs[rt][ct] + sb4;  // first write
        }
    }
}

// ---------------------------------------------------------------------------
// one WaveNet layer.  LDS = hh only (64 KB -> 2 blocks/CU).  Weights stream
// straight from L2 into VGPRs (lane-linear packed tiles, 1-step reg prefetch);
// the K-loops have NO barriers.  Only 3 __syncthreads per block:
// after hh staging, and around the gated overwrite of hh's shifted half.
//   hh row c (1024B, 64 16B-chunks, physical chunk p holds logical p^(c&7)):
//     logical  0..31 : h[t0+c][ch]           (res + filt/gate tap1)
//     logical 32..63 : h[t0+c-d][ch]  phase1 (filt/gate tap0)
//                      gated[c][ch]   phase2 (overwritten between barriers)
// ---------------------------------------------------------------------------
__global__ __launch_bounds__(512, 4) void layer_kernel(
    const ushort_t* __restrict__ h_in, ushort_t* __restrict__ h_out,
    float* __restrict__ fin,
    const char* __restrict__ WfL, const char* __restrict__ WgL,
    const char* __restrict__ WrL, const char* __restrict__ WsL,
    const float* __restrict__ fb_, const float* __restrict__ gb_,
    const float* __restrict__ rb_, const float* __restrict__ sb_,
    int d)
{
    __shared__ __align__(16) char hh[64 * 1024];

    const int tid = threadIdx.x;
    const int w = tid >> 6;
    const int ln = tid & 63;
    const int q = ln >> 4;
    const int n16 = ln & 15;
    const int lid = xcd_swz(blockIdx.x);
    const int b = lid >> 6;
    const int t0 = (lid & 63) * COLS;

    // ---- prologue: stage hh (pre-swizzled source, linear dest)
    const ushort_t* hbase = h_in + ((size_t)(b * TP + PADROWS + t0)) * L;
    #pragma unroll
    for (int it = 0; it < 8; ++it) {
        int c = it * 8 + w;                 // wave-uniform row
        int chunk = ln ^ (c & 7);           // pre-swizzled logical 16B-chunk
        int sh = (chunk >= 32) ? d : 0;
        const ushort_t* src = hbase + ((long)c - sh) * L + (chunk & 31) * 8;
        gld_lds16(src, hh + c * 1024);
    }
    __syncthreads();

    // per-wave weight stream pointers (lane-linear packed tiles)
    const char* pf = WfL + (w * 2) * 1024 + ln * 16;
    const char* pg = WgL + (w * 2) * 1024 + ln * 16;
    const char* ps = WsL + (w * 2) * 1024 + ln * 16;
    const char* pr = WrL + (w * 2) * 1024 + ln * 16;

    // ---- phase 1: filt & gate (K=512 concat), 16 K-steps, barrier-free
    f32x4 accf[2][4], accg[2][4];
    #pragma unroll
    for (int rt = 0; rt < 2; ++rt)
        #pragma unroll
        for (int ct = 0; ct < 4; ++ct) {
            accf[rt][ct] = (f32x4){0.f, 0.f, 0.f, 0.f};
            accg[rt][ct] = (f32x4){0.f, 0.f, 0.f, 0.f};
        }

    short8 wf0 = *(const short8*)(pf);
    short8 wf1 = *(const short8*)(pf + 1024);
    short8 wg0 = *(const short8*)(pg);
    short8 wg1 = *(const short8*)(pg + 1024);
    for (int st = 0; st < 16; ++st) {
        const int nb = ((st < 15) ? st + 1 : 15) * 16384;   // prefetch offset
        short8 nf0 = *(const short8*)(pf + nb);
        short8 nf1 = *(const short8*)(pf + nb + 1024);
        short8 ng0 = *(const short8*)(pg + nb);
        short8 ng1 = *(const short8*)(pg + nb + 1024);
        const int kq2 = st * 64 + q * 16;   // byte offset of this wave-q's k-chunk
        #pragma unroll
        for (int ct = 0; ct < 4; ++ct) {
            int c = ct * 16 + n16;
            short8 bfr = *(const short8*)(hh + c * 1024 + (kq2 ^ ((c & 7) << 4)));
            accf[0][ct] = mfma16(wf0, bfr, accf[0][ct]);
            accf[1][ct] = mfma16(wf1, bfr, accf[1][ct]);
            accg[0][ct] = mfma16(wg0, bfr, accg[0][ct]);
            accg[1][ct] = mfma16(wg1, bfr, accg[1][ct]);
        }
        wf0 = nf0; wf1 = nf1; wg0 = ng0; wg1 = ng1;
    }
    __syncthreads();   // all waves done reading hh's shifted half

    // ---- epilogue 1: gated = tanh(f+fb)*sigmoid(g+gb) -> hh logical 32..63
    const int row0 = w * 32;
    #pragma unroll
    for (int rt = 0; rt < 2; ++rt) {
        int i0 = row0 + rt * 16 + q * 4;
        f32x4 fb4 = *(const f32x4*)(fb_ + i0);
        f32x4 gb4 = *(const f32x4*)(gb_ + i0);
        #pragma unroll
        for (int ct = 0; ct < 4; ++ct) {
            int c = ct * 16 + n16;
            uint_t pk[2];
            #pragma unroll
            for (int h2 = 0; h2 < 2; ++h2) {
                float v0 = tanh_fast(accf[rt][ct][h2 * 2] + fb4[h2 * 2]) *
                           sigm_fast(accg[rt][ct][h2 * 2] + gb4[h2 * 2]);
                float v1 = tanh_fast(accf[rt][ct][h2 * 2 + 1] + fb4[h2 * 2 + 1]) *
                           sigm_fast(accg[rt][ct][h2 * 2 + 1] + gb4[h2 * 2 + 1]);
                pk[h2] = (uint_t)f2bf(v0) | ((uint_t)f2bf(v1) << 16);
            }
            int byt = c * 1024 + ((512 + i0 * 2) ^ ((c & 7) << 4));
            *(uint2*)(hh + byt) = make_uint2(pk[0], pk[1]);
        }
    }
    __syncthreads();

    // ---- phase 2: skip (gated, logical 512+2k) & res (2k), 8 steps, no barriers
    f32x4 accs[2][4], accr[2][4];
    #pragma unroll
    for (int rt = 0; rt < 2; ++rt)
        #pragma unroll
        for (int ct = 0; ct < 4; ++ct) {
            accs[rt][ct] = (f32x4){0.f, 0.f, 0.f, 0.f};
            accr[rt][ct] = (f32x4){0.f, 0.f, 0.f, 0.f};
        }

    short8 ws0 = *(const short8*)(ps);
    short8 ws1 = *(const short8*)(ps + 1024);
    short8 wr0 = *(const short8*)(pr);
    short8 wr1 = *(const short8*)(pr + 1024);
    for (int st = 0; st < 8; ++st) {
        const int nb = ((st < 7) ? st + 1 : 7) * 16384;
        short8 ns0 = *(const short8*)(ps + nb);
        short8 ns1 = *(const short8*)(ps + nb + 1024);
        short8 nr0 = *(const short8*)(pr + nb);
        short8 nr1 = *(const short8*)(pr + nb + 1024);
        const int kq2 = st * 64 + q * 16;
        #pragma unroll
        for (int ct = 0; ct < 4; ++ct) {
            int c = ct * 16 + n16;
            short8 bg = *(const short8*)(hh + c * 1024 +
                                         ((512 + kq2) ^ ((c & 7) << 4)));
            short8 bh = *(const short8*)(hh + c * 1024 + (kq2 ^ ((c & 7) << 4)));
            accs[0][ct] = mfma16(ws0, bg, accs[0][ct]);
            accs[1][ct] = mfma16(ws1, bg, accs[1][ct]);
            accr[0][ct] = mfma16(wr0, bh, accr[0][ct]);
            accr[1][ct] = mfma16(wr1, bh, accr[1][ct]);
        }
        ws0 = ns0; ws1 = ns1; wr0 = nr0; wr1 = nr1;
    }

    // ---- epilogue 2: h' = skip+res (bf16), final += skip (fp32 RMW)
    ushort_t* hob = h_out + ((size_t)(b * TP + PADROWS + t0)) * L;
    float* fob = fin + ((size_t)(b * Tn + t0)) * L;
    #pragma unroll
    for (int rt = 0; rt < 2; ++rt) {
        int i0 = row0 + rt * 16 + q * 4;
        f32x4 sb4 = *(const f32x4*)(sb_ + i0);
        f32x4 rb4 = *(const f32x4*)(rb_ + i0);
        #pragma unroll
        for (int ct = 0; ct < 4; ++ct) {
            int c = ct * 16 + n16;
            f32x4 sk = accs[rt][ct] + sb4;
            f32x4 hn = sk + accr[rt][ct] + rb4;
            uint_t lo = (uint_t)f2bf(hn[0]) | ((uint_t)f2bf(hn[1]) << 16);
            uint_t hi = (uint_t)f2bf(hn[2]) | ((uint_t)f2bf(hn[3]) << 16);
            *(uint2*)(hob + (size_t)c * L + i0) = make_uint2(lo, hi);
            f32x4* fp = (f32x4*)(fob + (size_t)c * L + i0);
            *fp = *fp + sk;
        }
    }
}

// ---------------------------------------------------------------------------
// head: relu->fin1->relu->fin2->out_w->tanh
// ---------------------------------------------------------------------------
__global__ __launch_bounds__(512, 4) void final_kernel(
    const float* __restrict__ fin,
    const ushort_t* __restrict__ W1, const float* __restrict__ b1,
    const ushort_t* __restrict__ W2, const float* __restrict__ b2,
    const ushort_t* __restrict__ Wo, const float* __restrict__ ob,
    float* __restrict__ out)
{
    __shared__ __align__(16) char s1[32 * 1024];
    __shared__ __align__(16) char s2[32 * 1024];

    const int tid = threadIdx.x;
    const int w = tid >> 6;
    const int ln = tid & 63;
    const int q = ln >> 4;
    const int n16 = ln & 15;
    const int lid = xcd_swz(blockIdx.x);
    const int b = lid >> 6;
    const int t0 = (lid & 63) * COLS;
    const int row0 = w * 32;

    // stage s1 = bf16(relu(final))
    {
        int c = tid & 63;
        int kg = tid >> 6;
        const float* fp = fin + ((size_t)(b * Tn + t0 + c)) * L + kg * 32;
        #pragma unroll
        for (int j = 0; j < 8; ++j) {
            f32x4 v = *(const f32x4*)(fp + j * 4);
            uint_t lo = (uint_t)f2bf(fmaxf(v[0], 0.f)) | ((uint_t)f2bf(fmaxf(v[1], 0.f)) << 16);
            uint_t hi = (uint_t)f2bf(fmaxf(v[2], 0.f)) | ((uint_t)f2bf(fmaxf(v[3], 0.f)) << 16);
            int kk = kg * 32 + j * 4;
            *(uint2*)(s1 + c * 512 + ((kk * 2) ^ ((c & 7) << 4))) = make_uint2(lo, hi);
        }
    }
    __syncthreads();

    // GEMM1: z1 = W1 @ s1; relu -> s2
    f32x4 acc[2][4];
    #pragma unroll
    for (int rt = 0; rt < 2; ++rt)
        #pragma unroll
        for (int ct = 0; ct < 4; ++ct) acc[rt][ct] = (f32x4){0.f, 0.f, 0.f, 0.f};
    for (int ks = 0; ks < 8; ++ks) {
        const int k = ks * 32 + q * 8;
        short8 bfr[4];
        #pragma unroll
        for (int ct = 0; ct < 4; ++ct) {
            int c = ct * 16 + n16;
            bfr[ct] = *(const short8*)(s1 + c * 512 + ((k * 2) ^ ((c & 7) << 4)));
        }
        #pragma unroll
        for (int rt = 0; rt < 2; ++rt) {
            int row = row0 + rt * 16 + n16;
            short8 a = *(const short8*)(W1 + row * L + k);
            #pragma unroll
            for (int ct = 0; ct < 4; ++ct) acc[rt][ct] = mfma16(a, bfr[ct], acc[rt][ct]);
        }
    }
    #pragma unroll
    for (int rt = 0; rt < 2; ++rt) {
        int i0 = row0 + rt * 16 + q * 4;
        f32x4 bb = *(const f32x4*)(b1 + i0);
        #pragma unroll
        for (int ct = 0; ct < 4; ++ct) {
            int c = ct * 16 + n16;
            f32x4 z = acc[rt][ct] + bb;
            uint_t lo = (uint_t)f2bf(fmaxf(z[0], 0.f)) | ((uint_t)f2bf(fmaxf(z[1], 0.f)) << 16);
            uint_t hi = (uint_t)f2bf(fmaxf(z[2], 0.f)) | ((uint_t)f2bf(fmaxf(z[3], 0.f)) << 16);
            *(uint2*)(s2 + c * 512 + ((i0 * 2) ^ ((c & 7) << 4))) = make_uint2(lo, hi);
        }
    }
    __syncthreads();

    // GEMM2: z2 = W2 @ s2 (no relu) -> s1
    #pragma unroll
    for (int rt = 0; rt < 2; ++rt)
        #pragma unroll
        for (int ct = 0; ct < 4; ++ct) acc[rt][ct] = (f32x4){0.f, 0.f, 0.f, 0.f};
    for (int ks = 0; ks < 8; ++ks) {
        const int k = ks * 32 + q * 8;
        short8 bfr[4];
        #pragma unroll
        for (int ct = 0; ct < 4; ++ct) {
            int c = ct * 16 + n16;
            bfr[ct] = *(const short8*)(s2 + c * 512 + ((k * 2) ^ ((c & 7) << 4)));
        }
        #pragma unroll
        for (int rt = 0; rt < 2; ++rt) {
            int row = row0 + rt * 16 + n16;
            short8 a = *(const short8*)(W2 + row * L + k);
            #pragma unroll
            for (int ct = 0; ct < 4; ++ct) acc[rt][ct] = mfma16(a, bfr[ct], acc[rt][ct]);
        }
    }
    #pragma unroll
    for (int rt = 0; rt < 2; ++rt) {
        int i0 = row0 + rt * 16 + q * 4;
        f32x4 bb = *(const f32x4*)(b2 + i0);
        #pragma unroll
        for (int ct = 0; ct < 4; ++ct) {
            int c = ct * 16 + n16;
            f32x4 z = acc[rt][ct] + bb;
            uint_t lo = (uint_t)f2bf(z[0]) | ((uint_t)f2bf(z[1]) << 16);
            uint_t hi = (uint_t)f2bf(z[2]) | ((uint_t)f2bf(z[3]) << 16);
            *(uint2*)(s1 + c * 512 + ((i0 * 2) ^ ((c & 7) << 4))) = make_uint2(lo, hi);
        }
    }
    __syncthreads();

    // GEMM3: out = tanh(Wo @ z2 + ob)  (M=64, waves 0..3)
    if (w < 4) {
        f32x4 acc3[4];
        #pragma unroll
        for (int ct = 0; ct < 4; ++ct) acc3[ct] = (f32x4){0.f, 0.f, 0.f, 0.f};
        for (int ks = 0; ks < 8; ++ks) {
            const int k = ks * 32 + q * 8;
            short8 bfr[4];
            #pragma unroll
            for (int ct = 0; ct < 4; ++ct) {
                int c = ct * 16 + n16;
                bfr[ct] = *(const short8*)(s1 + c * 512 + ((k * 2) ^ ((c & 7) << 4)));
            }
            short8 a = *(const short8*)(Wo + (w * 16 + n16) * L + k);
            #pragma unroll
            for (int ct = 0; ct < 4; ++ct) acc3[ct] = mfma16(a, bfr[ct], acc3[ct]);
        }
        int o0 = w * 16 + q * 4;
        f32x4 ob4 = *(const f32x4*)(ob + o0);
        float* obase = out + ((size_t)(b * Tn + t0)) * 64;
        #pragma unroll
        for (int ct = 0; ct < 4; ++ct) {
            int c = ct * 16 + n16;
            f32x4 v;
            #pragma unroll
            for (int j = 0; j < 4; ++j) v[j] = tanh_fast(acc3[ct][j] + ob4[j]);
            *(f32x4*)(obase + (size_t)c * 64 + o0) = v;
        }
    }
}

// ---------------------------------------------------------------------------
extern "C" void kernel_launch(void* const* d_in, const int* in_sizes, int n_in,
                              void* d_out, int out_size, void* d_ws, size_t ws_size,
                              hipStream_t stream)
{
    (void)in_sizes; (void)n_in; (void)out_size; (void)ws_size;
    const float* x      = (const float*)d_in[0];
    const float* emb_w  = (const float*)d_in[1];
    const float* emb_b  = (const float*)d_in[2];
    const float* filt_w = (const float*)d_in[3];
    const float* filt_b = (const float*)d_in[4];
    const float* gate_w = (const float*)d_in[5];
    const float* gate_b = (const float*)d_in[6];
    const float* res_w  = (const float*)d_in[7];
    const float* res_b  = (const float*)d_in[8];
    const float* skip_w = (const float*)d_in[9];
    const float* skip_b = (const float*)d_in[10];
    const float* fin1_w = (const float*)d_in[11];
    const float* fin1_b = (const float*)d_in[12];
    const float* fin2_w = (const float*)d_in[13];
    const float* fin2_b = (const float*)d_in[14];
    const float* out_w  = (const float*)d_in[15];
    const float* out_b  = (const float*)d_in[16];

    char* ws = (char*)d_ws;
    size_t off = 0;
    auto alloc = [&](size_t bytes) -> char* {
        char* p = ws + off;
        off += (bytes + 255) & ~(size_t)255;
        return p;
    };
    ushort_t* h_a = (ushort_t*)alloc((size_t)Bn * TP * L * 2);
    ushort_t* h_b = (ushort_t*)alloc((size_t)Bn * TP * L * 2);
    float*    fin = (float*)   alloc((size_t)Bn * Tn * L * 4);
    ushort_t* Wfp = (ushort_t*)alloc((size_t)NL * 16 * 1024 * 8 * 2);
    ushort_t* Wgp = (ushort_t*)alloc((size_t)NL * 16 * 1024 * 8 * 2);
    ushort_t* Wrp = (ushort_t*)alloc((size_t)NL * 8 * 1024 * 8 * 2);
    ushort_t* Wsp = (ushort_t*)alloc((size_t)NL * 8 * 1024 * 8 * 2);
    ushort_t* Ws0 = (ushort_t*)alloc((size_t)L * L * 2);
    ushort_t* We  = (ushort_t*)alloc((size_t)L * IN_DIM * 2);
    ushort_t* W1  = (ushort_t*)alloc((size_t)L * L * 2);
    ushort_t* W2  = (ushort_t*)alloc((size_t)L * L * 2);
    ushort_t* Wo  = (ushort_t*)alloc((size_t)64 * L * 2);

    prep_kernel<<<512, 256, 0, stream>>>(filt_w, gate_w, res_w, skip_w, emb_w,
        fin1_w, fin2_w, out_w, Wfp, Wgp, Wrp, Wsp, Ws0, We, W1, W2, Wo, h_a, h_b);

    emb_kernel<<<1024, 512, 0, stream>>>(x, We, emb_b, Ws0, skip_b, h_a, fin);

    ushort_t* hin = h_a;
    ushort_t* hout = h_b;
    for (int i = 0; i < NL; ++i) {
        layer_kernel<<<1024, 512, 0, stream>>>(hin, hout, fin,
            (const char*)Wfp + (size_t)i * 16 * 16384,
            (const char*)Wgp + (size_t)i * 16 * 16384,
            (const char*)Wrp + (size_t)i * 8 * 16384,
            (const char*)Wsp + (size_t)i * 8 * 16384,
            filt_b + i * L, gate_b + i * L, res_b + i * L, skip_b + (i + 1) * L,
            1 << i);
        ushort_t* t = hin; hin = hout; hout = t;
    }

    final_kernel<<<1024, 512, 0, stream>>>(fin, W1, fin1_b, W2, fin2_b,
        Wo, out_b, (float*)d_out);
}

// Round 8
// 965.311 us; speedup vs baseline: 1.5154x; 1.0635x over previous
//
#include <hip/hip_runtime.h>
#include <hip/hip_bf16.h>

#define Bn 16
#define Tn 4096
#define IN_DIM 64
#define L 256
#define NL 10
#define PADROWS 512
#define TP (Tn + PADROWS)   // 4608
#define COLS 64

typedef __attribute__((ext_vector_type(8))) short short8;
typedef __attribute__((ext_vector_type(4))) float f32x4;
typedef unsigned short ushort_t;
typedef unsigned int uint_t;

__device__ inline ushort_t f2bf(float f) {
    uint_t u = __builtin_bit_cast(uint_t, f);
    u = u + 0x7fffu + ((u >> 16) & 1u);
    return (ushort_t)(u >> 16);
}
__device__ inline float bf2f(ushort_t v) {
    uint_t u = ((uint_t)v) << 16;
    return __builtin_bit_cast(float, u);
}

__device__ inline float fexp2f(float x) { return __builtin_amdgcn_exp2f(x); }
__device__ inline float frcpf(float x)  { return __builtin_amdgcn_rcpf(x); }
__device__ inline float tanh_fast(float x) {
    float e = fexp2f(x * 2.8853900817779268f);   // e^(2x)
    return 1.f - 2.f * frcpf(e + 1.f);
}
__device__ inline float sigm_fast(float x) {
    return frcpf(1.f + fexp2f(-1.4426950408889634f * x));
}

__device__ inline f32x4 mfma16(short8 a, short8 b, f32x4 c) {
    return __builtin_amdgcn_mfma_f32_16x16x32_bf16(a, b, c, 0, 0, 0);
}

__device__ inline void gld_lds16(const void* src, void* dst) {
    __builtin_amdgcn_global_load_lds(
        (const __attribute__((address_space(1))) void*)src,
        (__attribute__((address_space(3))) void*)dst, 16, 0, 0);
}

// bijective XCD-chunked swizzle for grid=1024 (1024 % 8 == 0, chunk=128)
__device__ inline int xcd_swz(int bid) {
    return (bid & 7) * 128 + (bid >> 3);
}

// ---------------------------------------------------------------------------
// prep: fp32 weights -> bf16, packed lane-linear per K-step:
//   [steps][16 rgrp][4 q][16 r][8 e]  (wave w, step t, fragment rt at
//   t*16384 + (2w+rt)*1024 + lane*16 -- fully coalesced 16B/lane)
// Also zero h pads.
// ---------------------------------------------------------------------------
__global__ void prep_kernel(
    const float* __restrict__ filt_w, const float* __restrict__ gate_w,
    const float* __restrict__ res_w,  const float* __restrict__ skip_w,
    const float* __restrict__ emb_w,  const float* __restrict__ fin1_w,
    const float* __restrict__ fin2_w, const float* __restrict__ out_w,
    ushort_t* __restrict__ Wfp, ushort_t* __restrict__ Wgp,
    ushort_t* __restrict__ Wrp, ushort_t* __restrict__ Wsp,
    ushort_t* __restrict__ Ws0, ushort_t* __restrict__ We,
    ushort_t* __restrict__ W1,  ushort_t* __restrict__ W2,
    ushort_t* __restrict__ Wo,
    ushort_t* __restrict__ h_a, ushort_t* __restrict__ h_b)
{
    const int stride = gridDim.x * blockDim.x;
    const int tid0 = blockIdx.x * blockDim.x + threadIdx.x;

    // filt/gate packed: [NL][16 steps][16 rg][4 q][16 r][8 e]
    // concat K: k<256 -> tap1 (unshifted h), k>=256 -> tap0 (shifted h)
    for (int idx = tid0; idx < NL * 16 * 1024 * 8; idx += stride) {
        int e  = idx & 7;
        int r  = (idx >> 3) & 15;
        int qq = (idx >> 7) & 3;
        int rg = (idx >> 9) & 15;
        int t  = (idx >> 13) & 15;
        int i  = idx >> 17;
        int row = rg * 16 + r;
        int k = t * 32 + qq * 8 + e;
        int tap = (k < 256) ? 1 : 0;
        int kk = k & 255;
        int src = ((i * 256 + row) * 256 + kk) * 2 + tap;
        Wfp[idx] = f2bf(filt_w[src]);
        Wgp[idx] = f2bf(gate_w[src]);
    }
    // res / skip(1..10) packed: [NL][8 steps][16 rg][4 q][16 r][8 e]
    for (int idx = tid0; idx < NL * 8 * 1024 * 8; idx += stride) {
        int e  = idx & 7;
        int r  = (idx >> 3) & 15;
        int qq = (idx >> 7) & 3;
        int rg = (idx >> 9) & 15;
        int t  = (idx >> 13) & 7;
        int i  = idx >> 16;
        int row = rg * 16 + r;
        int k = t * 32 + qq * 8 + e;
        Wrp[idx] = f2bf(res_w[(i * 256 + row) * 256 + k]);
        Wsp[idx] = f2bf(skip_w[((i + 1) * 256 + row) * 256 + k]);
    }
    // row-major small weights
    for (int idx = tid0; idx < L * L; idx += stride) {
        Ws0[idx] = f2bf(skip_w[idx]);
        W1[idx] = f2bf(fin1_w[idx]);
        W2[idx] = f2bf(fin2_w[idx]);
    }
    for (int idx = tid0; idx < L * IN_DIM; idx += stride) We[idx] = f2bf(emb_w[idx]);
    for (int idx = tid0; idx < 64 * L; idx += stride)     Wo[idx] = f2bf(out_w[idx]);
    // zero the 512-row time pads of both h buffers
    for (int idx = tid0; idx < Bn * PADROWS * L; idx += stride) {
        int bb = idx >> 17;            // 512*256 = 1<<17
        int r = idx & 131071;
        size_t off = (size_t)bb * TP * L + r;
        h_a[off] = 0;
        h_b[off] = 0;
    }
}

// ---------------------------------------------------------------------------
// embedding: h0 = relu(We @ x^T + eb); skip0 = Ws0 @ h0 + sb0
//   SLAB: skip0 stored as bf16 slab.   !SLAB: stored as fp32 fin (first write).
// ---------------------------------------------------------------------------
template<bool SLAB>
__global__ __launch_bounds__(512, 4) void emb_kernel(
    const float* __restrict__ x,
    const ushort_t* __restrict__ We, const float* __restrict__ eb,
    const ushort_t* __restrict__ Ws0, const float* __restrict__ sb0,
    ushort_t* __restrict__ h_out, ushort_t* __restrict__ skip0,
    float* __restrict__ fin)
{
    __shared__ __align__(16) char gt[32 * 1024];   // [64][256] bf16, chunk-swizzled

    const int tid = threadIdx.x;
    const int w = tid >> 6;
    const int ln = tid & 63;
    const int q = ln >> 4;
    const int n16 = ln & 15;
    const int lid = xcd_swz(blockIdx.x);
    const int b = lid >> 6;
    const int t0 = (lid & 63) * COLS;
    const int row0 = w * 32;

    f32x4 acc[2][4];
    #pragma unroll
    for (int rt = 0; rt < 2; ++rt)
        #pragma unroll
        for (int ct = 0; ct < 4; ++ct) acc[rt][ct] = (f32x4){0.f, 0.f, 0.f, 0.f};

    #pragma unroll
    for (int ks = 0; ks < 2; ++ks) {
        const int k = ks * 32 + q * 8;
        short8 bfr[4];
        #pragma unroll
        for (int ct = 0; ct < 4; ++ct) {
            int c = ct * 16 + n16;
            const float* xp = x + ((size_t)(b * Tn + t0 + c)) * IN_DIM + k;
            f32x4 x0 = *(const f32x4*)xp;
            f32x4 x1 = *(const f32x4*)(xp + 4);
            short8 v;
            v[0] = (short)f2bf(x0[0]); v[1] = (short)f2bf(x0[1]);
            v[2] = (short)f2bf(x0[2]); v[3] = (short)f2bf(x0[3]);
            v[4] = (short)f2bf(x1[0]); v[5] = (short)f2bf(x1[1]);
            v[6] = (short)f2bf(x1[2]); v[7] = (short)f2bf(x1[3]);
            bfr[ct] = v;
        }
        #pragma unroll
        for (int rt = 0; rt < 2; ++rt) {
            int row = row0 + rt * 16 + n16;
            short8 a = *(const short8*)(We + row * IN_DIM + k);
            #pragma unroll
            for (int ct = 0; ct < 4; ++ct)
                acc[rt][ct] = mfma16(a, bfr[ct], acc[rt][ct]);
        }
    }

    // epilogue: h0 = relu(acc + eb) -> global h + LDS gt
    ushort_t* hob = h_out + ((size_t)(b * TP + PADROWS + t0)) * L;
    #pragma unroll
    for (int rt = 0; rt < 2; ++rt) {
        int i0 = row0 + rt * 16 + q * 4;
        f32x4 eb4 = *(const f32x4*)(eb + i0);
        #pragma unroll
        for (int ct = 0; ct < 4; ++ct) {
            int c = ct * 16 + n16;
            f32x4 h0 = acc[rt][ct] + eb4;
            float v0 = fmaxf(h0[0], 0.f), v1 = fmaxf(h0[1], 0.f);
            float v2 = fmaxf(h0[2], 0.f), v3 = fmaxf(h0[3], 0.f);
            uint_t lo = (uint_t)f2bf(v0) | ((uint_t)f2bf(v1) << 16);
            uint_t hi = (uint_t)f2bf(v2) | ((uint_t)f2bf(v3) << 16);
            *(uint2*)(hob + (size_t)c * L + i0) = make_uint2(lo, hi);
            int byt = c * 512 + ((i0 * 2) ^ ((c & 7) << 4));
            *(uint2*)(gt + byt) = make_uint2(lo, hi);
        }
    }
    __syncthreads();

    // skip0 GEMM over gt
    f32x4 accs[2][4];
    #pragma unroll
    for (int rt = 0; rt < 2; ++rt)
        #pragma unroll
        for (int ct = 0; ct < 4; ++ct) accs[rt][ct] = (f32x4){0.f, 0.f, 0.f, 0.f};

    for (int ks = 0; ks < 8; ++ks) {
        const int k = ks * 32 + q * 8;
        short8 bg[4];
        #pragma unroll
        for (int ct = 0; ct < 4; ++ct) {
            int c = ct * 16 + n16;
            bg[ct] = *(const short8*)(gt + c * 512 + ((k * 2) ^ ((c & 7) << 4)));
        }
        #pragma unroll
        for (int rt = 0; rt < 2; ++rt) {
            int row = row0 + rt * 16 + n16;
            short8 a = *(const short8*)(Ws0 + row * L + k);
            #pragma unroll
            for (int ct = 0; ct < 4; ++ct)
                accs[rt][ct] = mfma16(a, bg[ct], accs[rt][ct]);
        }
    }
    #pragma unroll
    for (int rt = 0; rt < 2; ++rt) {
        int i0 = row0 + rt * 16 + q * 4;
        f32x4 sb4 = *(const f32x4*)(sb0 + i0);
        #pragma unroll
        for (int ct = 0; ct < 4; ++ct) {
            int c = ct * 16 + n16;
            f32x4 z = accs[rt][ct] + sb4;
            if constexpr (SLAB) {
                ushort_t* sob = skip0 + ((size_t)(b * Tn + t0)) * L;
                uint_t lo = (uint_t)f2bf(z[0]) | ((uint_t)f2bf(z[1]) << 16);
                uint_t hi = (uint_t)f2bf(z[2]) | ((uint_t)f2bf(z[3]) << 16);
                *(uint2*)(sob + (size_t)c * L + i0) = make_uint2(lo, hi);
            } else {
                float* fob = fin + ((size_t)(b * Tn + t0)) * L;
                *(f32x4*)(fob + (size_t)c * L + i0) = z;   // first write
            }
        }
    }
}

// ---------------------------------------------------------------------------
// one WaveNet layer.  LDS = hh only (64 KB -> 2 blocks/CU).  Weights stream
// from L2 into VGPRs (lane-linear packed, 1-step reg prefetch); K-loops are
// barrier-free.  Epilogue bounces hn/sk through hh, then copy-out is fully
// coalesced.  SLAB: sk -> bf16 slab.   !SLAB: sk accumulated into fp32 fin
// (coalesced 1KB-row RMW).
//   hh row c (1024B): bytes 0..511 = h[t0+c] (phases) then hn (epi);
//                     512..1023 = h[t0+c-d] (ph1), gated (ph2), sk (epi).
//   LDS addresses XOR-swizzled by ((c&7)<<4) within each 512B half.
// ---------------------------------------------------------------------------
template<bool SLAB>
__global__ __launch_bounds__(512, 4) void layer_kernel(
    const ushort_t* __restrict__ h_in, ushort_t* __restrict__ h_out,
    ushort_t* __restrict__ skip_out, float* __restrict__ fin,
    const char* __restrict__ WfL, const char* __restrict__ WgL,
    const char* __restrict__ WrL, const char* __restrict__ WsL,
    const float* __restrict__ fb_, const float* __restrict__ gb_,
    const float* __restrict__ rb_, const float* __restrict__ sb_,
    int d)
{
    __shared__ __align__(16) char hh[64 * 1024];

    const int tid = threadIdx.x;
    const int w = tid >> 6;
    const int ln = tid & 63;
    const int q = ln >> 4;
    const int n16 = ln & 15;
    const int lid = xcd_swz(blockIdx.x);
    const int b = lid >> 6;
    const int t0 = (lid & 63) * COLS;

    // ---- prologue: stage hh (pre-swizzled source, linear dest)
    const ushort_t* hbase = h_in + ((size_t)(b * TP + PADROWS + t0)) * L;
    #pragma unroll
    for (int it = 0; it < 8; ++it) {
        int c = it * 8 + w;                 // wave-uniform row
        int chunk = ln ^ (c & 7);           // pre-swizzled logical 16B-chunk
        int sh = (chunk >= 32) ? d : 0;
        const ushort_t* src = hbase + ((long)c - sh) * L + (chunk & 31) * 8;
        gld_lds16(src, hh + c * 1024);
    }
    __syncthreads();

    // per-wave weight stream pointers (lane-linear packed tiles)
    const char* pf = WfL + (w * 2) * 1024 + ln * 16;
    const char* pg = WgL + (w * 2) * 1024 + ln * 16;
    const char* ps = WsL + (w * 2) * 1024 + ln * 16;
    const char* pr = WrL + (w * 2) * 1024 + ln * 16;

    // ---- phase 1: filt & gate (K=512 concat), 16 K-steps, barrier-free
    f32x4 accf[2][4], accg[2][4];
    #pragma unroll
    for (int rt = 0; rt < 2; ++rt)
        #pragma unroll
        for (int ct = 0; ct < 4; ++ct) {
            accf[rt][ct] = (f32x4){0.f, 0.f, 0.f, 0.f};
            accg[rt][ct] = (f32x4){0.f, 0.f, 0.f, 0.f};
        }

    short8 wf0 = *(const short8*)(pf);
    short8 wf1 = *(const short8*)(pf + 1024);
    short8 wg0 = *(const short8*)(pg);
    short8 wg1 = *(const short8*)(pg + 1024);
    for (int st = 0; st < 16; ++st) {
        const int nb = ((st < 15) ? st + 1 : 15) * 16384;   // prefetch offset
        short8 nf0 = *(const short8*)(pf + nb);
        short8 nf1 = *(const short8*)(pf + nb + 1024);
        short8 ng0 = *(const short8*)(pg + nb);
        short8 ng1 = *(const short8*)(pg + nb + 1024);
        const int kq2 = st * 64 + q * 16;   // byte offset of this wave-q's k-chunk
        #pragma unroll
        for (int ct = 0; ct < 4; ++ct) {
            int c = ct * 16 + n16;
            short8 bfr = *(const short8*)(hh + c * 1024 + (kq2 ^ ((c & 7) << 4)));
            accf[0][ct] = mfma16(wf0, bfr, accf[0][ct]);
            accf[1][ct] = mfma16(wf1, bfr, accf[1][ct]);
            accg[0][ct] = mfma16(wg0, bfr, accg[0][ct]);
            accg[1][ct] = mfma16(wg1, bfr, accg[1][ct]);
        }
        wf0 = nf0; wf1 = nf1; wg0 = ng0; wg1 = ng1;
    }
    __syncthreads();   // all waves done reading hh's shifted half

    // ---- epilogue 1: gated = tanh(f+fb)*sigmoid(g+gb) -> hh bytes 512..1023
    const int row0 = w * 32;
    #pragma unroll
    for (int rt = 0; rt < 2; ++rt) {
        int i0 = row0 + rt * 16 + q * 4;
        f32x4 fb4 = *(const f32x4*)(fb_ + i0);
        f32x4 gb4 = *(const f32x4*)(gb_ + i0);
        #pragma unroll
        for (int ct = 0; ct < 4; ++ct) {
            int c = ct * 16 + n16;
            uint_t pk[2];
            #pragma unroll
            for (int h2 = 0; h2 < 2; ++h2) {
                float v0 = tanh_fast(accf[rt][ct][h2 * 2] + fb4[h2 * 2]) *
                           sigm_fast(accg[rt][ct][h2 * 2] + gb4[h2 * 2]);
                float v1 = tanh_fast(accf[rt][ct][h2 * 2 + 1] + fb4[h2 * 2 + 1]) *
                           sigm_fast(accg[rt][ct][h2 * 2 + 1] + gb4[h2 * 2 + 1]);
                pk[h2] = (uint_t)f2bf(v0) | ((uint_t)f2bf(v1) << 16);
            }
            int byt = c * 1024 + 512 + ((i0 * 2) ^ ((c & 7) << 4));
            *(uint2*)(hh + byt) = make_uint2(pk[0], pk[1]);
        }
    }
    __syncthreads();

    // ---- phase 2: skip (gated, upper half) & res (lower half), 8 steps
    f32x4 accs[2][4], accr[2][4];
    #pragma unroll
    for (int rt = 0; rt < 2; ++rt)
        #pragma unroll
        for (int ct = 0; ct < 4; ++ct) {
            accs[rt][ct] = (f32x4){0.f, 0.f, 0.f, 0.f};
            accr[rt][ct] = (f32x4){0.f, 0.f, 0.f, 0.f};
        }

    short8 ws0 = *(const short8*)(ps);
    short8 ws1 = *(const short8*)(ps + 1024);
    short8 wr0 = *(const short8*)(pr);
    short8 wr1 = *(const short8*)(pr + 1024);
    for (int st = 0; st < 8; ++st) {
        const int nb = ((st < 7) ? st + 1 : 7) * 16384;
        short8 ns0 = *(const short8*)(ps + nb);
        short8 ns1 = *(const short8*)(ps + nb + 1024);
        short8 nr0 = *(const short8*)(pr + nb);
        short8 nr1 = *(const short8*)(pr + nb + 1024);
        const int kq2 = st * 64 + q * 16;
        #pragma unroll
        for (int ct = 0; ct < 4; ++ct) {
            int c = ct * 16 + n16;
            short8 bg = *(const short8*)(hh + c * 1024 + 512 +
                                         (kq2 ^ ((c & 7) << 4)));
            short8 bh = *(const short8*)(hh + c * 1024 + (kq2 ^ ((c & 7) << 4)));
            accs[0][ct] = mfma16(ws0, bg, accs[0][ct]);
            accs[1][ct] = mfma16(ws1, bg, accs[1][ct]);
            accr[0][ct] = mfma16(wr0, bh, accr[0][ct]);
            accr[1][ct] = mfma16(wr1, bh, accr[1][ct]);
        }
        ws0 = ns0; ws1 = ns1; wr0 = nr0; wr1 = nr1;
    }
    __syncthreads();   // all waves done reading hh before epilogue overwrite

    // ---- epilogue 2: hn = sk+res -> hh bytes 0..511; sk -> bytes 512..1023
    #pragma unroll
    for (int rt = 0; rt < 2; ++rt) {
        int i0 = row0 + rt * 16 + q * 4;
        f32x4 sb4 = *(const f32x4*)(sb_ + i0);
        f32x4 rb4 = *(const f32x4*)(rb_ + i0);
        #pragma unroll
        for (int ct = 0; ct < 4; ++ct) {
            int c = ct * 16 + n16;
            f32x4 sk = accs[rt][ct] + sb4;
            f32x4 hn = sk + accr[rt][ct] + rb4;
            uint_t hlo = (uint_t)f2bf(hn[0]) | ((uint_t)f2bf(hn[1]) << 16);
            uint_t hhi = (uint_t)f2bf(hn[2]) | ((uint_t)f2bf(hn[3]) << 16);
            uint_t slo = (uint_t)f2bf(sk[0]) | ((uint_t)f2bf(sk[1]) << 16);
            uint_t shi = (uint_t)f2bf(sk[2]) | ((uint_t)f2bf(sk[3]) << 16);
            int sw = (i0 * 2) ^ ((c & 7) << 4);
            *(uint2*)(hh + c * 1024 + sw) = make_uint2(hlo, hhi);
            *(uint2*)(hh + c * 1024 + 512 + sw) = make_uint2(slo, shi);
        }
    }
    __syncthreads();

    // ---- coalesced copy-out
    ushort_t* hob = h_out + ((size_t)(b * TP + PADROWS + t0)) * L;
    #pragma unroll
    for (int it = 0; it < 8; ++it) {
        int c = it * 8 + w;
        short8 v = *(const short8*)(hh + c * 1024 + ((ln * 16) ^ ((c & 7) << 4)));
        if constexpr (SLAB) {
            ushort_t* sob = skip_out + ((size_t)(b * Tn + t0)) * L;
            if (ln < 32) *(short8*)(hob + (size_t)c * L + ln * 8) = v;
            else         *(short8*)(sob + (size_t)c * L + (ln - 32) * 8) = v;
        } else {
            if (ln < 32) *(short8*)(hob + (size_t)c * L + ln * 8) = v;
            // fin += sk : coalesced 1KB-row fp32 RMW (4 floats/lane)
            uint2 skb = *(const uint2*)(hh + c * 1024 + 512 +
                                        ((ln * 8) ^ ((c & 7) << 4)));
            float* fp = fin + ((size_t)(b * Tn + t0 + c)) * L + ln * 4;
            f32x4 f = *(const f32x4*)fp;
            f[0] += bf2f((ushort_t)(skb.x & 0xffff));
            f[1] += bf2f((ushort_t)(skb.x >> 16));
            f[2] += bf2f((ushort_t)(skb.y & 0xffff));
            f[3] += bf2f((ushort_t)(skb.y >> 16));
            *(f32x4*)fp = f;
        }
    }
}

// ---------------------------------------------------------------------------
// head: final = sum(slabs) [SLAB] or fp32 fin [!SLAB];
// relu->fin1->relu->fin2->out_w->tanh
// ---------------------------------------------------------------------------
template<bool SLAB>
__global__ __launch_bounds__(512, 4) void final_kernel(
    const ushort_t* __restrict__ skipbase, size_t slab,
    const float* __restrict__ fin,
    const ushort_t* __restrict__ W1, const float* __restrict__ b1,
    const ushort_t* __restrict__ W2, const float* __restrict__ b2,
    const ushort_t* __restrict__ Wo, const float* __restrict__ ob,
    float* __restrict__ out)
{
    __shared__ __align__(16) char s1[32 * 1024];
    __shared__ __align__(16) char s2[32 * 1024];

    const int tid = threadIdx.x;
    const int w = tid >> 6;
    const int ln = tid & 63;
    const int q = ln >> 4;
    const int n16 = ln & 15;
    const int lid = xcd_swz(blockIdx.x);
    const int b = lid >> 6;
    const int t0 = (lid & 63) * COLS;
    const int row0 = w * 32;

    // ---- stage s1 = bf16(relu(final))
    if constexpr (SLAB) {
        const int c = tid >> 3;            // 0..63
        const int j0 = tid & 7;            // base 16B-chunk
        const size_t rowoff = ((size_t)(b * Tn + t0 + c)) * L;
        float acc[4][8];
        #pragma unroll
        for (int jj = 0; jj < 4; ++jj)
            #pragma unroll
            for (int e = 0; e < 8; ++e) acc[jj][e] = 0.f;
        for (int l = 0; l < NL + 1; ++l) {
            const ushort_t* sp = skipbase + (size_t)l * slab + rowoff;
            #pragma unroll
            for (int jj = 0; jj < 4; ++jj) {
                short8 v = *(const short8*)(sp + j0 * 8 + jj * 64);
                #pragma unroll
                for (int e = 0; e < 8; ++e)
                    acc[jj][e] += bf2f((ushort_t)v[e]);
            }
        }
        #pragma unroll
        for (int jj = 0; jj < 4; ++jj) {
            short8 v;
            #pragma unroll
            for (int e = 0; e < 8; ++e)
                v[e] = (short)f2bf(fmaxf(acc[jj][e], 0.f));
            int j = j0 + jj * 8;
            *(short8*)(s1 + c * 512 + ((j * 16) ^ ((c & 7) << 4))) = v;
        }
    } else {
        int c = tid & 63;
        int kg = tid >> 6;
        const float* fp = fin + ((size_t)(b * Tn + t0 + c)) * L + kg * 32;
        #pragma unroll
        for (int j = 0; j < 8; ++j) {
            f32x4 v = *(const f32x4*)(fp + j * 4);
            uint_t lo = (uint_t)f2bf(fmaxf(v[0], 0.f)) | ((uint_t)f2bf(fmaxf(v[1], 0.f)) << 16);
            uint_t hi = (uint_t)f2bf(fmaxf(v[2], 0.f)) | ((uint_t)f2bf(fmaxf(v[3], 0.f)) << 16);
            int kk = kg * 32 + j * 4;
            *(uint2*)(s1 + c * 512 + ((kk * 2) ^ ((c & 7) << 4))) = make_uint2(lo, hi);
        }
    }
    __syncthreads();

    // GEMM1: z1 = W1 @ s1; relu -> s2
    f32x4 acc[2][4];
    #pragma unroll
    for (int rt = 0; rt < 2; ++rt)
        #pragma unroll
        for (int ct = 0; ct < 4; ++ct) acc[rt][ct] = (f32x4){0.f, 0.f, 0.f, 0.f};
    for (int ks = 0; ks < 8; ++ks) {
        const int k = ks * 32 + q * 8;
        short8 bfr[4];
        #pragma unroll
        for (int ct = 0; ct < 4; ++ct) {
            int c = ct * 16 + n16;
            bfr[ct] = *(const short8*)(s1 + c * 512 + ((k * 2) ^ ((c & 7) << 4)));
        }
        #pragma unroll
        for (int rt = 0; rt < 2; ++rt) {
            int row = row0 + rt * 16 + n16;
            short8 a = *(const short8*)(W1 + row * L + k);
            #pragma unroll
            for (int ct = 0; ct < 4; ++ct) acc[rt][ct] = mfma16(a, bfr[ct], acc[rt][ct]);
        }
    }
    #pragma unroll
    for (int rt = 0; rt < 2; ++rt) {
        int i0 = row0 + rt * 16 + q * 4;
        f32x4 bb = *(const f32x4*)(b1 + i0);
        #pragma unroll
        for (int ct = 0; ct < 4; ++ct) {
            int c = ct * 16 + n16;
            f32x4 z = acc[rt][ct] + bb;
            uint_t lo = (uint_t)f2bf(fmaxf(z[0], 0.f)) | ((uint_t)f2bf(fmaxf(z[1], 0.f)) << 16);
            uint_t hi = (uint_t)f2bf(fmaxf(z[2], 0.f)) | ((uint_t)f2bf(fmaxf(z[3], 0.f)) << 16);
            *(uint2*)(s2 + c * 512 + ((i0 * 2) ^ ((c & 7) << 4))) = make_uint2(lo, hi);
        }
    }
    __syncthreads();

    // GEMM2: z2 = W2 @ s2 (no relu) -> s1
    #pragma unroll
    for (int rt = 0; rt < 2; ++rt)
        #pragma unroll
        for (int ct = 0; ct < 4; ++ct) acc[rt][ct] = (f32x4){0.f, 0.f, 0.f, 0.f};
    for (int ks = 0; ks < 8; ++ks) {
        const int k = ks * 32 + q * 8;
        short8 bfr[4];
        #pragma unroll
        for (int ct = 0; ct < 4; ++ct) {
            int c = ct * 16 + n16;
            bfr[ct] = *(const short8*)(s2 + c * 512 + ((k * 2) ^ ((c & 7) << 4)));
        }
        #pragma unroll
        for (int rt = 0; rt < 2; ++rt) {
            int row = row0 + rt * 16 + n16;
            short8 a = *(const short8*)(W2 + row * L + k);
            #pragma unroll
            for (int ct = 0; ct < 4; ++ct) acc[rt][ct] = mfma16(a, bfr[ct], acc[rt][ct]);
        }
    }
    #pragma unroll
    for (int rt = 0; rt < 2; ++rt) {
        int i0 = row0 + rt * 16 + q * 4;
        f32x4 bb = *(const f32x4*)(b2 + i0);
        #pragma unroll
        for (int ct = 0; ct < 4; ++ct) {
            int c = ct * 16 + n16;
            f32x4 z = acc[rt][ct] + bb;
            uint_t lo = (uint_t)f2bf(z[0]) | ((uint_t)f2bf(z[1]) << 16);
            uint_t hi = (uint_t)f2bf(z[2]) | ((uint_t)f2bf(z[3]) << 16);
            *(uint2*)(s1 + c * 512 + ((i0 * 2) ^ ((c & 7) << 4))) = make_uint2(lo, hi);
        }
    }
    __syncthreads();

    // GEMM3: out = tanh(Wo @ z2 + ob)  (M=64, waves 0..3)
    if (w < 4) {
        f32x4 acc3[4];
        #pragma unroll
        for (int ct = 0; ct < 4; ++ct) acc3[ct] = (f32x4){0.f, 0.f, 0.f, 0.f};
        for (int ks = 0; ks < 8; ++ks) {
            const int k = ks * 32 + q * 8;
            short8 bfr[4];
            #pragma unroll
            for (int ct = 0; ct < 4; ++ct) {
                int c = ct * 16 + n16;
                bfr[ct] = *(const short8*)(s1 + c * 512 + ((k * 2) ^ ((c & 7) << 4)));
            }
            short8 a = *(const short8*)(Wo + (w * 16 + n16) * L + k);
            #pragma unroll
            for (int ct = 0; ct < 4; ++ct) acc3[ct] = mfma16(a, bfr[ct], acc3[ct]);
        }
        int o0 = w * 16 + q * 4;
        f32x4 ob4 = *(const f32x4*)(ob + o0);
        float* obase = out + ((size_t)(b * Tn + t0)) * 64;
        #pragma unroll
        for (int ct = 0; ct < 4; ++ct) {
            int c = ct * 16 + n16;
            f32x4 v;
            #pragma unroll
            for (int j = 0; j < 4; ++j) v[j] = tanh_fast(acc3[ct][j] + ob4[j]);
            *(f32x4*)(obase + (size_t)c * 64 + o0) = v;
        }
    }
}

// ---------------------------------------------------------------------------
extern "C" void kernel_launch(void* const* d_in, const int* in_sizes, int n_in,
                              void* d_out, int out_size, void* d_ws, size_t ws_size,
                              hipStream_t stream)
{
    (void)in_sizes; (void)n_in; (void)out_size;
    const float* x      = (const float*)d_in[0];
    const float* emb_w  = (const float*)d_in[1];
    const float* emb_b  = (const float*)d_in[2];
    const float* filt_w = (const float*)d_in[3];
    const float* filt_b = (const float*)d_in[4];
    const float* gate_w = (const float*)d_in[5];
    const float* gate_b = (const float*)d_in[6];
    const float* res_w  = (const float*)d_in[7];
    const float* res_b  = (const float*)d_in[8];
    const float* skip_w = (const float*)d_in[9];
    const float* skip_b = (const float*)d_in[10];
    const float* fin1_w = (const float*)d_in[11];
    const float* fin1_b = (const float*)d_in[12];
    const float* fin2_w = (const float*)d_in[13];
    const float* fin2_b = (const float*)d_in[14];
    const float* out_w  = (const float*)d_in[15];
    const float* out_b  = (const float*)d_in[16];

    const size_t SLAB = (size_t)Bn * Tn * L;               // elements
    const size_t sz_h     = (size_t)Bn * TP * L * 2;       // 37.75 MB
    const size_t sz_slabs = (size_t)(NL + 1) * SLAB * 2;   // 369 MB
    const size_t sz_fin   = (size_t)Bn * Tn * L * 4;       // 67 MB
    const size_t sz_wfg   = (size_t)NL * 16 * 1024 * 8 * 2;
    const size_t sz_wrs   = (size_t)NL * 8 * 1024 * 8 * 2;
    const size_t sz_small = 3 * (size_t)L * L * 2 + (size_t)L * IN_DIM * 2 +
                            (size_t)64 * L * 2 + 4096;
    const size_t reqA = 2 * sz_h + sz_slabs + 2 * sz_wfg + 2 * sz_wrs + sz_small;
    const bool useSlab = (ws_size >= reqA);

    char* ws = (char*)d_ws;
    size_t off = 0;
    auto alloc = [&](size_t bytes) -> char* {
        char* p = ws + off;
        off += (bytes + 255) & ~(size_t)255;
        return p;
    };
    ushort_t* h_a   = (ushort_t*)alloc(sz_h);
    ushort_t* h_b   = (ushort_t*)alloc(sz_h);
    ushort_t* skipb = nullptr;
    float*    fin   = nullptr;
    if (useSlab) skipb = (ushort_t*)alloc(sz_slabs);
    else         fin   = (float*)alloc(sz_fin);
    ushort_t* Wfp = (ushort_t*)alloc(sz_wfg);
    ushort_t* Wgp = (ushort_t*)alloc(sz_wfg);
    ushort_t* Wrp = (ushort_t*)alloc(sz_wrs);
    ushort_t* Wsp = (ushort_t*)alloc(sz_wrs);
    ushort_t* Ws0 = (ushort_t*)alloc((size_t)L * L * 2);
    ushort_t* We  = (ushort_t*)alloc((size_t)L * IN_DIM * 2);
    ushort_t* W1  = (ushort_t*)alloc((size_t)L * L * 2);
    ushort_t* W2  = (ushort_t*)alloc((size_t)L * L * 2);
    ushort_t* Wo  = (ushort_t*)alloc((size_t)64 * L * 2);

    prep_kernel<<<512, 256, 0, stream>>>(filt_w, gate_w, res_w, skip_w, emb_w,
        fin1_w, fin2_w, out_w, Wfp, Wgp, Wrp, Wsp, Ws0, We, W1, W2, Wo, h_a, h_b);

    if (useSlab) {
        emb_kernel<true><<<1024, 512, 0, stream>>>(x, We, emb_b, Ws0, skip_b,
            h_a, skipb, nullptr);
        ushort_t* hin = h_a;
        ushort_t* hout = h_b;
        for (int i = 0; i < NL; ++i) {
            layer_kernel<true><<<1024, 512, 0, stream>>>(hin, hout,
                skipb + (size_t)(i + 1) * SLAB, nullptr,
                (const char*)Wfp + (size_t)i * 16 * 16384,
                (const char*)Wgp + (size_t)i * 16 * 16384,
                (const char*)Wrp + (size_t)i * 8 * 16384,
                (const char*)Wsp + (size_t)i * 8 * 16384,
                filt_b + i * L, gate_b + i * L, res_b + i * L,
                skip_b + (i + 1) * L, 1 << i);
            ushort_t* t = hin; hin = hout; hout = t;
        }
        final_kernel<true><<<1024, 512, 0, stream>>>(skipb, SLAB, nullptr,
            W1, fin1_b, W2, fin2_b, Wo, out_b, (float*)d_out);
    } else {
        emb_kernel<false><<<1024, 512, 0, stream>>>(x, We, emb_b, Ws0, skip_b,
            h_a, nullptr, fin);
        ushort_t* hin = h_a;
        ushort_t* hout = h_b;
        for (int i = 0; i < NL; ++i) {
            layer_kernel<false><<<1024, 512, 0, stream>>>(hin, hout,
                nullptr, fin,
                (const char*)Wfp + (size_t)i * 16 * 16384,
                (const char*)Wgp + (size_t)i * 16 * 16384,
                (const char*)Wrp + (size_t)i * 8 * 16384,
                (const char*)Wsp + (size_t)i * 8 * 16384,
                filt_b + i * L, gate_b + i * L, res_b + i * L,
                skip_b + (i + 1) * L, 1 << i);
            ushort_t* t = hin; hin = hout; hout = t;
        }
        final_kernel<false><<<1024, 512, 0, stream>>>(nullptr, SLAB, fin,
            W1, fin1_b, W2, fin2_b, Wo, out_b, (float*)d_out);
    }
}